// Round 1
// baseline (2288.585 us; speedup 1.0000x reference)
//
#include <hip/hip_runtime.h>

typedef unsigned short u16;
typedef __attribute__((ext_vector_type(8))) short short8;
typedef __attribute__((ext_vector_type(4))) float floatx4;

#define N_NODESC 100000
#define N_EDGESC 1600000
#define N_GRAPHSC 256
#define F_INC 128
#define HDIM 256
#define SCAN_CHUNK 512
#define SCAN_NB ((N_NODESC + SCAN_CHUNK - 1) / SCAN_CHUNK)  // 196

__device__ __forceinline__ float bf2f(u16 u) {
    union { unsigned int i; float f; } v; v.i = ((unsigned int)u) << 16; return v.f;
}
__device__ __forceinline__ u16 f2bf(float f) {
    union { float f; unsigned int i; } v; v.f = f;
    unsigned int b = v.i;
    b += 0x7fffu + ((b >> 16) & 1u);
    return (u16)(b >> 16);
}

// ---------- weight prep: out[c*K + k] = (k<K1 ? Wl[k][c] : Wr[k-K1][c]) as bf16 ----------
__global__ void k_wcat(const float* __restrict__ Wl, const float* __restrict__ Wr,
                       int K1, int K2, u16* __restrict__ out) {
    int K = K1 + K2;
    int idx = blockIdx.x * 256 + threadIdx.x;
    if (idx >= 256 * K) return;
    int c = idx / K, k = idx - c * K;
    float v = (k < K1) ? Wl[k * 256 + c] : Wr[(k - K1) * 256 + c];
    out[idx] = f2bf(v);
}

// ---------- fp32 -> bf16 vectorized convert ----------
__global__ void k_f2bf4(const float* __restrict__ in, u16* __restrict__ out, int n4) {
    int i = blockIdx.x * 256 + threadIdx.x;
    if (i >= n4) return;
    float4 v = ((const float4*)in)[i];
    ushort4 o = make_ushort4(f2bf(v.x), f2bf(v.y), f2bf(v.z), f2bf(v.w));
    ((ushort4*)out)[i] = o;
}

// ---------- histogram ----------
__global__ void k_count(const int* __restrict__ ids, int* __restrict__ cnt, int n) {
    int i = blockIdx.x * 256 + threadIdx.x;
    if (i < n) atomicAdd(&cnt[ids[i]], 1);
}

// ---------- 3-phase scan over counts -> csr_ptr ----------
__global__ void k_scan_bsum(const int* __restrict__ cnt, int* __restrict__ bsum, int n) {
    __shared__ int ts[256];
    int t = threadIdx.x;
    int i0 = blockIdx.x * SCAN_CHUNK + t * 2;
    int c0 = (i0 < n) ? cnt[i0] : 0;
    int c1 = (i0 + 1 < n) ? cnt[i0 + 1] : 0;
    ts[t] = c0 + c1;
    __syncthreads();
    for (int off = 128; off > 0; off >>= 1) {
        if (t < off) ts[t] += ts[t + off];
        __syncthreads();
    }
    if (t == 0) bsum[blockIdx.x] = ts[0];
}

__global__ void k_scan_boff(const int* __restrict__ bsum, int* __restrict__ boff, int nb) {
    __shared__ int ts[256];
    int t = threadIdx.x;
    int v = (t < nb) ? bsum[t] : 0;
    ts[t] = v;
    __syncthreads();
    for (int off = 1; off < 256; off <<= 1) {
        int u = (t >= off) ? ts[t - off] : 0;
        __syncthreads();
        ts[t] += u;
        __syncthreads();
    }
    if (t < nb) boff[t] = ts[t] - v;  // exclusive
}

__global__ void k_scan_write(const int* __restrict__ cnt, const int* __restrict__ boff,
                             int* __restrict__ cptr, int n) {
    __shared__ int ts[256];
    int t = threadIdx.x;
    int i0 = blockIdx.x * SCAN_CHUNK + t * 2;
    int c0 = (i0 < n) ? cnt[i0] : 0;
    int c1 = (i0 + 1 < n) ? cnt[i0 + 1] : 0;
    int ms = c0 + c1;
    ts[t] = ms;
    __syncthreads();
    for (int off = 1; off < 256; off <<= 1) {
        int u = (t >= off) ? ts[t - off] : 0;
        __syncthreads();
        ts[t] += u;
        __syncthreads();
    }
    int excl = ts[t] - ms + boff[blockIdx.x];
    if (i0 < n) cptr[i0] = excl;
    if (i0 + 1 < n) cptr[i0 + 1] = excl + c0;
    if (i0 == n - 1) cptr[n] = excl + c0;
    else if (i0 + 1 == n - 1) cptr[n] = excl + c0 + c1;
}

__global__ void k_deginv(const int* __restrict__ cnt, float* __restrict__ di, int n) {
    int i = blockIdx.x * 256 + threadIdx.x;
    if (i < n) di[i] = 1.0f / (float)(cnt[i] > 1 ? cnt[i] : 1);
}

__global__ void k_fill(const int* __restrict__ src, const int* __restrict__ dst,
                       const int* __restrict__ cptr, int* __restrict__ fillc,
                       int* __restrict__ adj, int E) {
    int e = blockIdx.x * 256 + threadIdx.x;
    if (e >= E) return;
    int d = dst[e];
    int pos = atomicAdd(&fillc[d], 1);
    adj[cptr[d] + pos] = src[e];
}

// ---------- aggregation: one wave per node, lane holds F/64 features ----------
template <int F>
__global__ void k_aggregate(const u16* __restrict__ hin, const int* __restrict__ cptr,
                            const int* __restrict__ adj, const float* __restrict__ di,
                            u16* __restrict__ out, int n) {
    constexpr int V = F / 64;
    int lane = threadIdx.x & 63;
    int node = blockIdx.x * 4 + (threadIdx.x >> 6);
    if (node >= n) return;
    int p0 = cptr[node], p1 = cptr[node + 1];
    const u16* base = hin + (size_t)lane * V;
    float d = di[node];
    if constexpr (V == 4) {
        float a0 = 0.f, a1 = 0.f, a2 = 0.f, a3 = 0.f;
        int j = p0;
        for (; j + 3 < p1; j += 4) {
            int s0 = adj[j], s1 = adj[j + 1], s2 = adj[j + 2], s3 = adj[j + 3];
            ushort4 h0 = *(const ushort4*)(base + (size_t)s0 * F);
            ushort4 h1 = *(const ushort4*)(base + (size_t)s1 * F);
            ushort4 h2 = *(const ushort4*)(base + (size_t)s2 * F);
            ushort4 h3 = *(const ushort4*)(base + (size_t)s3 * F);
            a0 += bf2f(h0.x) + bf2f(h1.x) + bf2f(h2.x) + bf2f(h3.x);
            a1 += bf2f(h0.y) + bf2f(h1.y) + bf2f(h2.y) + bf2f(h3.y);
            a2 += bf2f(h0.z) + bf2f(h1.z) + bf2f(h2.z) + bf2f(h3.z);
            a3 += bf2f(h0.w) + bf2f(h1.w) + bf2f(h2.w) + bf2f(h3.w);
        }
        for (; j < p1; ++j) {
            ushort4 h0 = *(const ushort4*)(base + (size_t)adj[j] * F);
            a0 += bf2f(h0.x); a1 += bf2f(h0.y); a2 += bf2f(h0.z); a3 += bf2f(h0.w);
        }
        ushort4 o = make_ushort4(f2bf(a0 * d), f2bf(a1 * d), f2bf(a2 * d), f2bf(a3 * d));
        *(ushort4*)(out + (size_t)node * F + lane * 4) = o;
    } else {
        float a0 = 0.f, a1 = 0.f;
        int j = p0;
        for (; j + 3 < p1; j += 4) {
            int s0 = adj[j], s1 = adj[j + 1], s2 = adj[j + 2], s3 = adj[j + 3];
            ushort2 h0 = *(const ushort2*)(base + (size_t)s0 * F);
            ushort2 h1 = *(const ushort2*)(base + (size_t)s1 * F);
            ushort2 h2 = *(const ushort2*)(base + (size_t)s2 * F);
            ushort2 h3 = *(const ushort2*)(base + (size_t)s3 * F);
            a0 += bf2f(h0.x) + bf2f(h1.x) + bf2f(h2.x) + bf2f(h3.x);
            a1 += bf2f(h0.y) + bf2f(h1.y) + bf2f(h2.y) + bf2f(h3.y);
        }
        for (; j < p1; ++j) {
            ushort2 h0 = *(const ushort2*)(base + (size_t)adj[j] * F);
            a0 += bf2f(h0.x); a1 += bf2f(h0.y);
        }
        ushort2 o; o.x = f2bf(a0 * d); o.y = f2bf(a1 * d);
        *(ushort2*)(out + (size_t)node * F + lane * 2) = o;
    }
}

// ---------- GEMM: C[M,256] = A1[:, :K1] ++ A2[:, :K2] times W (Wt is [256][K] bf16) ----------
__global__ __launch_bounds__(256) void k_gemm(
    const u16* __restrict__ A1, int K1,
    const u16* __restrict__ A2, int K2,
    const u16* __restrict__ Wt,
    u16* __restrict__ C, int M) {
    const int K = K1 + K2;
    __shared__ __align__(16) u16 Al[128 * 40];
    __shared__ __align__(16) u16 Bl[128 * 40];
    const int t = threadIdx.x;
    const int lane = t & 63;
    const int wave = t >> 6;
    const int wr = (wave >> 1) * 64, wc = (wave & 1) * 64;
    const int quad = lane >> 4, l15 = lane & 15;
    const int rowBase = blockIdx.x * 128;
    const int colBase = blockIdx.y * 128;

    floatx4 acc[4][4];
#pragma unroll
    for (int i = 0; i < 4; ++i)
#pragma unroll
        for (int j = 0; j < 4; ++j)
            acc[i][j] = (floatx4){0.f, 0.f, 0.f, 0.f};

    const int r0 = t >> 2;             // 0..63
    const int ch0 = (t & 3) * 8;       // 0,8,16,24 (elements)

    for (int kt = 0; kt < K; kt += 32) {
        const u16* As; int lda, kloc;
        if (kt < K1) { As = A1; lda = K1; kloc = kt; }
        else         { As = A2; lda = K2; kloc = kt - K1; }
#pragma unroll
        for (int l = 0; l < 2; ++l) {
            const int r = r0 + l * 64;
            const int grow = rowBase + r;
            uint4 va = make_uint4(0u, 0u, 0u, 0u);
            if (grow < M) va = *(const uint4*)(As + (size_t)grow * lda + (kloc + ch0));
            *(uint4*)(Al + r * 40 + ch0) = va;
            uint4 vb = *(const uint4*)(Wt + (size_t)(colBase + r) * K + (kt + ch0));
            *(uint4*)(Bl + r * 40 + ch0) = vb;
        }
        __syncthreads();
        short8 af[4], bfr[4];
#pragma unroll
        for (int i = 0; i < 4; ++i) af[i] = *(const short8*)(Al + (wr + i * 16 + l15) * 40 + quad * 8);
#pragma unroll
        for (int j = 0; j < 4; ++j) bfr[j] = *(const short8*)(Bl + (wc + j * 16 + l15) * 40 + quad * 8);
#pragma unroll
        for (int i = 0; i < 4; ++i)
#pragma unroll
            for (int j = 0; j < 4; ++j)
                acc[i][j] = __builtin_amdgcn_mfma_f32_16x16x32_bf16(af[i], bfr[j], acc[i][j], 0, 0, 0);
        __syncthreads();
    }
#pragma unroll
    for (int i = 0; i < 4; ++i) {
#pragma unroll
        for (int r = 0; r < 4; ++r) {
            const int row = rowBase + wr + i * 16 + quad * 4 + r;
            if (row < M) {
#pragma unroll
                for (int j = 0; j < 4; ++j) {
                    const int col = colBase + wc + j * 16 + l15;
                    C[(size_t)row * HDIM + col] = f2bf(acc[i][j][r]);
                }
            }
        }
    }
}

// ---------- column stats (sum, sumsq) ----------
__global__ void k_colstats(const u16* __restrict__ Cb, float* __restrict__ stats, int M) {
    const int c = threadIdx.x;
    const int rpb = (M + gridDim.x - 1) / gridDim.x;
    int r0 = blockIdx.x * rpb;
    int r1 = r0 + rpb; if (r1 > M) r1 = M;
    float s = 0.f, ss = 0.f;
    for (int r = r0; r < r1; ++r) {
        float v = bf2f(Cb[(size_t)r * HDIM + c]);
        s += v; ss += v * v;
    }
    atomicAdd(&stats[c], s);
    atomicAdd(&stats[HDIM + c], ss);
}

__global__ void k_bnscale(const float* __restrict__ stats, const float* __restrict__ g,
                          const float* __restrict__ beta, float* __restrict__ sc,
                          float* __restrict__ sh, float invN) {
    int c = threadIdx.x;
    float mu = stats[c] * invN;
    float var = stats[HDIM + c] * invN - mu * mu;
    float s = g[c] * rsqrtf(var + 1e-5f);
    sc[c] = s;
    sh[c] = beta[c] - mu * s;
}

// ---------- h_next = relu(C*scale+shift) + identity (+res_b) ----------
__global__ void k_finalize(const u16* __restrict__ Cb, const u16* __restrict__ iden,
                           const float* __restrict__ sc, const float* __restrict__ sh,
                           const float* __restrict__ resb,
                           u16* __restrict__ hout, int n8) {
    int i = blockIdx.x * 256 + threadIdx.x;
    if (i >= n8) return;
    const int c0 = (i * 8) & (HDIM - 1);
    const ushort4* cp = (const ushort4*)Cb;
    const ushort4* ip = (const ushort4*)iden;
    ushort4 cv0 = cp[2 * i], cv1 = cp[2 * i + 1];
    ushort4 iv0 = ip[2 * i], iv1 = ip[2 * i + 1];
    u16 cc[8] = {cv0.x, cv0.y, cv0.z, cv0.w, cv1.x, cv1.y, cv1.z, cv1.w};
    u16 dd[8] = {iv0.x, iv0.y, iv0.z, iv0.w, iv1.x, iv1.y, iv1.z, iv1.w};
    u16 oo[8];
#pragma unroll
    for (int e = 0; e < 8; ++e) {
        const int c = c0 + e;
        float v = bf2f(cc[e]) * sc[c] + sh[c];
        v = fmaxf(v, 0.f) + bf2f(dd[e]);
        if (resb) v += resb[c];
        oo[e] = f2bf(v);
    }
    ushort4* op = (ushort4*)hout;
    op[2 * i]     = make_ushort4(oo[0], oo[1], oo[2], oo[3]);
    op[2 * i + 1] = make_ushort4(oo[4], oo[5], oo[6], oo[7]);
}

// ---------- readout: per-node dot(h, lin_W), atomic into per-graph sum ----------
__global__ void k_readout(const u16* __restrict__ h, const float* __restrict__ w,
                          const int* __restrict__ batch, float* __restrict__ gsum, int n) {
    int lane = threadIdx.x & 63;
    int node = blockIdx.x * 4 + (threadIdx.x >> 6);
    if (node >= n) return;
    ushort4 hv = *(const ushort4*)(h + (size_t)node * HDIM + lane * 4);
    float4 wv = *(const float4*)(w + lane * 4);
    float s = bf2f(hv.x) * wv.x + bf2f(hv.y) * wv.y + bf2f(hv.z) * wv.z + bf2f(hv.w) * wv.w;
#pragma unroll
    for (int off = 32; off > 0; off >>= 1) s += __shfl_down(s, off);
    if (lane == 0) atomicAdd(&gsum[batch[node]], s);
}

__global__ void k_final(const float* __restrict__ gsum, const int* __restrict__ cntb,
                        const float* __restrict__ lb, float* __restrict__ out) {
    int g = threadIdx.x;
    int c = cntb[g]; if (c < 1) c = 1;
    out[g] = gsum[g] / (float)c + lb[0];
}

extern "C" void kernel_launch(void* const* d_in, const int* in_sizes, int n_in,
                              void* d_out, int out_size, void* d_ws, size_t ws_size,
                              hipStream_t stream) {
    const float* x     = (const float*)d_in[0];
    const int*   ei    = (const int*)d_in[1];
    const int*   batch = (const int*)d_in[2];
    const float* Wl1 = (const float*)d_in[3];
    const float* Wr1 = (const float*)d_in[5];
    const float* g1  = (const float*)d_in[6];
    const float* be1 = (const float*)d_in[7];
    const float* Wl2 = (const float*)d_in[8];
    const float* Wr2 = (const float*)d_in[10];
    const float* g2  = (const float*)d_in[11];
    const float* be2 = (const float*)d_in[12];
    const float* Wl3 = (const float*)d_in[13];
    const float* Wr3 = (const float*)d_in[15];
    const float* g3  = (const float*)d_in[16];
    const float* be3 = (const float*)d_in[17];
    const float* Wl4 = (const float*)d_in[18];
    const float* Wr4 = (const float*)d_in[20];
    const float* g4  = (const float*)d_in[21];
    const float* be4 = (const float*)d_in[22];
    const float* resW = (const float*)d_in[23];
    const float* resb = (const float*)d_in[24];
    const float* linW = (const float*)d_in[25];
    const float* linb = (const float*)d_in[26];
    float* out = (float*)d_out;

    char* p = (char*)d_ws;
    auto carve = [&](size_t bytes) -> char* {
        char* r = p;
        p += (bytes + 255) & ~(size_t)255;
        return r;
    };
    int*   cptr   = (int*)carve((size_t)(N_NODESC + 1) * 4);
    int*   counts = (int*)carve((size_t)N_NODESC * 4);
    int*   fillc  = (int*)carve((size_t)N_NODESC * 4);
    float* dinv   = (float*)carve((size_t)N_NODESC * 4);
    int*   cntb   = (int*)carve(N_GRAPHSC * 4);
    float* gsum   = (float*)carve(N_GRAPHSC * 4);
    float* stats  = (float*)carve(4 * 512 * 4);
    float* scale  = (float*)carve(256 * 4);
    float* shift  = (float*)carve(256 * 4);
    int*   bsum   = (int*)carve(SCAN_NB * 4);
    int*   boff   = (int*)carve(SCAN_NB * 4);
    int*   adj    = (int*)carve((size_t)N_EDGESC * 4);
    u16*   Wt1    = (u16*)carve(256 * 256 * 2);
    u16*   Wt2    = (u16*)carve(256 * 512 * 2);
    u16*   Wt3    = (u16*)carve(256 * 512 * 2);
    u16*   Wt4    = (u16*)carve(256 * 512 * 2);
    u16*   Rt     = (u16*)carve(256 * 128 * 2);
    u16*   xb     = (u16*)carve((size_t)N_NODESC * F_INC * 2);
    u16*   hA     = (u16*)carve((size_t)N_NODESC * HDIM * 2);
    u16*   hB     = (u16*)carve((size_t)N_NODESC * HDIM * 2);
    u16*   agg    = (u16*)carve((size_t)N_NODESC * HDIM * 2);  // aliased as res for layer 1
    u16*   Cb     = (u16*)carve((size_t)N_NODESC * HDIM * 2);

    hipMemsetAsync(counts, 0, (size_t)N_NODESC * 4, stream);
    hipMemsetAsync(fillc, 0, (size_t)N_NODESC * 4, stream);
    hipMemsetAsync(cntb, 0, N_GRAPHSC * 4, stream);
    hipMemsetAsync(gsum, 0, N_GRAPHSC * 4, stream);
    hipMemsetAsync(stats, 0, 4 * 512 * 4, stream);

    const int* srcp = ei;
    const int* dstp = ei + N_EDGESC;

    // weight prep + x conversion
    k_wcat<<<(256 * 256 + 255) / 256, 256, 0, stream>>>(Wl1, Wr1, 128, 128, Wt1);
    k_wcat<<<(256 * 512 + 255) / 256, 256, 0, stream>>>(Wl2, Wr2, 256, 256, Wt2);
    k_wcat<<<(256 * 512 + 255) / 256, 256, 0, stream>>>(Wl3, Wr3, 256, 256, Wt3);
    k_wcat<<<(256 * 512 + 255) / 256, 256, 0, stream>>>(Wl4, Wr4, 256, 256, Wt4);
    k_wcat<<<(256 * 128 + 255) / 256, 256, 0, stream>>>(resW, resW, 128, 0, Rt);
    k_f2bf4<<<(N_NODESC * F_INC / 4 + 255) / 256, 256, 0, stream>>>(x, xb, N_NODESC * F_INC / 4);

    // graph structure
    k_count<<<(N_EDGESC + 255) / 256, 256, 0, stream>>>(dstp, counts, N_EDGESC);
    k_count<<<(N_NODESC + 255) / 256, 256, 0, stream>>>(batch, cntb, N_NODESC);
    k_scan_bsum<<<SCAN_NB, 256, 0, stream>>>(counts, bsum, N_NODESC);
    k_scan_boff<<<1, 256, 0, stream>>>(bsum, boff, SCAN_NB);
    k_scan_write<<<SCAN_NB, 256, 0, stream>>>(counts, boff, cptr, N_NODESC);
    k_deginv<<<(N_NODESC + 255) / 256, 256, 0, stream>>>(counts, dinv, N_NODESC);
    k_fill<<<(N_EDGESC + 255) / 256, 256, 0, stream>>>(srcp, dstp, cptr, fillc, adj, N_EDGESC);

    dim3 gGemm(782, 2);
    const float invN = 1.0f / (float)N_NODESC;
    const int n8 = N_NODESC * HDIM / 8;
    const int finBlocks = (n8 + 255) / 256;

    // ---- layer 1 ----
    k_aggregate<128><<<25000, 256, 0, stream>>>(xb, cptr, adj, dinv, agg, N_NODESC);
    k_gemm<<<gGemm, 256, 0, stream>>>(agg, 128, xb, 128, Wt1, Cb, N_NODESC);
    k_gemm<<<gGemm, 256, 0, stream>>>(xb, 128, xb, 0, Rt, agg, N_NODESC);  // res reuses agg
    k_colstats<<<256, 256, 0, stream>>>(Cb, stats, N_NODESC);
    k_bnscale<<<1, 256, 0, stream>>>(stats, g1, be1, scale, shift, invN);
    k_finalize<<<finBlocks, 256, 0, stream>>>(Cb, agg, scale, shift, resb, hA, n8);

    // ---- layer 2 ----
    k_aggregate<256><<<25000, 256, 0, stream>>>(hA, cptr, adj, dinv, agg, N_NODESC);
    k_gemm<<<gGemm, 256, 0, stream>>>(agg, 256, hA, 256, Wt2, Cb, N_NODESC);
    k_colstats<<<256, 256, 0, stream>>>(Cb, stats + 512, N_NODESC);
    k_bnscale<<<1, 256, 0, stream>>>(stats + 512, g2, be2, scale, shift, invN);
    k_finalize<<<finBlocks, 256, 0, stream>>>(Cb, hA, scale, shift, nullptr, hB, n8);

    // ---- layer 3 ----
    k_aggregate<256><<<25000, 256, 0, stream>>>(hB, cptr, adj, dinv, agg, N_NODESC);
    k_gemm<<<gGemm, 256, 0, stream>>>(agg, 256, hB, 256, Wt3, Cb, N_NODESC);
    k_colstats<<<256, 256, 0, stream>>>(Cb, stats + 1024, N_NODESC);
    k_bnscale<<<1, 256, 0, stream>>>(stats + 1024, g3, be3, scale, shift, invN);
    k_finalize<<<finBlocks, 256, 0, stream>>>(Cb, hB, scale, shift, nullptr, hA, n8);

    // ---- layer 4 ----
    k_aggregate<256><<<25000, 256, 0, stream>>>(hA, cptr, adj, dinv, agg, N_NODESC);
    k_gemm<<<gGemm, 256, 0, stream>>>(agg, 256, hA, 256, Wt4, Cb, N_NODESC);
    k_colstats<<<256, 256, 0, stream>>>(Cb, stats + 1536, N_NODESC);
    k_bnscale<<<1, 256, 0, stream>>>(stats + 1536, g4, be4, scale, shift, invN);
    k_finalize<<<finBlocks, 256, 0, stream>>>(Cb, hA, scale, shift, nullptr, hB, n8);

    // ---- pooled @ lin_W + lin_b  ==  seg_mean(h @ lin_W) + lin_b ----
    k_readout<<<25000, 256, 0, stream>>>(hB, linW, batch, gsum, N_NODESC);
    k_final<<<1, 256, 0, stream>>>(gsum, cntb, linb, out);
}

// Round 2
// 1958.646 us; speedup vs baseline: 1.1685x; 1.1685x over previous
//
#include <hip/hip_runtime.h>

typedef unsigned short u16;
typedef __attribute__((ext_vector_type(8))) short short8;
typedef __attribute__((ext_vector_type(4))) float floatx4;

#define N_NODESC 100000
#define N_EDGESC 1600000
#define N_GRAPHSC 256
#define F_INC 128
#define HDIM 256
#define SCAN_CHUNK 512
#define SCAN_NB ((N_NODESC + SCAN_CHUNK - 1) / SCAN_CHUNK)  // 196

__device__ __forceinline__ float bf2f(u16 u) {
    union { unsigned int i; float f; } v; v.i = ((unsigned int)u) << 16; return v.f;
}
__device__ __forceinline__ u16 f2bf(float f) {
    union { float f; unsigned int i; } v; v.f = f;
    unsigned int b = v.i;
    b += 0x7fffu + ((b >> 16) & 1u);
    return (u16)(b >> 16);
}

// ---------- weight prep: out[c*K + k] = (k<K1 ? Wl[k][c] : Wr[k-K1][c]) as bf16 ----------
__global__ void k_wcat(const float* __restrict__ Wl, const float* __restrict__ Wr,
                       int K1, int K2, u16* __restrict__ out) {
    int K = K1 + K2;
    int idx = blockIdx.x * 256 + threadIdx.x;
    if (idx >= 256 * K) return;
    int c = idx / K, k = idx - c * K;
    float v = (k < K1) ? Wl[k * 256 + c] : Wr[(k - K1) * 256 + c];
    out[idx] = f2bf(v);
}

// ---------- fp32 -> bf16 vectorized convert ----------
__global__ void k_f2bf4(const float* __restrict__ in, u16* __restrict__ out, int n4) {
    int i = blockIdx.x * 256 + threadIdx.x;
    if (i >= n4) return;
    float4 v = ((const float4*)in)[i];
    ushort4 o = make_ushort4(f2bf(v.x), f2bf(v.y), f2bf(v.z), f2bf(v.w));
    ((ushort4*)out)[i] = o;
}

// ---------- histogram ----------
__global__ void k_count(const int* __restrict__ ids, int* __restrict__ cnt, int n) {
    int i = blockIdx.x * 256 + threadIdx.x;
    if (i < n) atomicAdd(&cnt[ids[i]], 1);
}

// ---------- 3-phase scan over counts -> csr_ptr ----------
__global__ void k_scan_bsum(const int* __restrict__ cnt, int* __restrict__ bsum, int n) {
    __shared__ int ts[256];
    int t = threadIdx.x;
    int i0 = blockIdx.x * SCAN_CHUNK + t * 2;
    int c0 = (i0 < n) ? cnt[i0] : 0;
    int c1 = (i0 + 1 < n) ? cnt[i0 + 1] : 0;
    ts[t] = c0 + c1;
    __syncthreads();
    for (int off = 128; off > 0; off >>= 1) {
        if (t < off) ts[t] += ts[t + off];
        __syncthreads();
    }
    if (t == 0) bsum[blockIdx.x] = ts[0];
}

__global__ void k_scan_boff(const int* __restrict__ bsum, int* __restrict__ boff, int nb) {
    __shared__ int ts[256];
    int t = threadIdx.x;
    int v = (t < nb) ? bsum[t] : 0;
    ts[t] = v;
    __syncthreads();
    for (int off = 1; off < 256; off <<= 1) {
        int u = (t >= off) ? ts[t - off] : 0;
        __syncthreads();
        ts[t] += u;
        __syncthreads();
    }
    if (t < nb) boff[t] = ts[t] - v;  // exclusive
}

__global__ void k_scan_write(const int* __restrict__ cnt, const int* __restrict__ boff,
                             int* __restrict__ cptr, int n) {
    __shared__ int ts[256];
    int t = threadIdx.x;
    int i0 = blockIdx.x * SCAN_CHUNK + t * 2;
    int c0 = (i0 < n) ? cnt[i0] : 0;
    int c1 = (i0 + 1 < n) ? cnt[i0 + 1] : 0;
    int ms = c0 + c1;
    ts[t] = ms;
    __syncthreads();
    for (int off = 1; off < 256; off <<= 1) {
        int u = (t >= off) ? ts[t - off] : 0;
        __syncthreads();
        ts[t] += u;
        __syncthreads();
    }
    int excl = ts[t] - ms + boff[blockIdx.x];
    if (i0 < n) cptr[i0] = excl;
    if (i0 + 1 < n) cptr[i0 + 1] = excl + c0;
    if (i0 == n - 1) cptr[n] = excl + c0;
    else if (i0 + 1 == n - 1) cptr[n] = excl + c0 + c1;
}

__global__ void k_deginv(const int* __restrict__ cnt, float* __restrict__ di, int n) {
    int i = blockIdx.x * 256 + threadIdx.x;
    if (i < n) di[i] = 1.0f / (float)(cnt[i] > 1 ? cnt[i] : 1);
}

__global__ void k_fill(const int* __restrict__ src, const int* __restrict__ dst,
                       const int* __restrict__ cptr, int* __restrict__ fillc,
                       int* __restrict__ adj, int E) {
    int e = blockIdx.x * 256 + threadIdx.x;
    if (e >= E) return;
    int d = dst[e];
    int pos = atomicAdd(&fillc[d], 1);
    adj[cptr[d] + pos] = src[e];
}

// ---------- aggregation: one wave per node, lane holds F/64 features ----------
template <int F>
__global__ void k_aggregate(const u16* __restrict__ hin, const int* __restrict__ cptr,
                            const int* __restrict__ adj, const float* __restrict__ di,
                            u16* __restrict__ out, int n) {
    constexpr int V = F / 64;
    int lane = threadIdx.x & 63;
    int node = blockIdx.x * 4 + (threadIdx.x >> 6);
    if (node >= n) return;
    int p0 = cptr[node], p1 = cptr[node + 1];
    const u16* base = hin + (size_t)lane * V;
    float d = di[node];
    if constexpr (V == 4) {
        float a0 = 0.f, a1 = 0.f, a2 = 0.f, a3 = 0.f;
        int j = p0;
        for (; j + 3 < p1; j += 4) {
            int s0 = adj[j], s1 = adj[j + 1], s2 = adj[j + 2], s3 = adj[j + 3];
            ushort4 h0 = *(const ushort4*)(base + (size_t)s0 * F);
            ushort4 h1 = *(const ushort4*)(base + (size_t)s1 * F);
            ushort4 h2 = *(const ushort4*)(base + (size_t)s2 * F);
            ushort4 h3 = *(const ushort4*)(base + (size_t)s3 * F);
            a0 += bf2f(h0.x) + bf2f(h1.x) + bf2f(h2.x) + bf2f(h3.x);
            a1 += bf2f(h0.y) + bf2f(h1.y) + bf2f(h2.y) + bf2f(h3.y);
            a2 += bf2f(h0.z) + bf2f(h1.z) + bf2f(h2.z) + bf2f(h3.z);
            a3 += bf2f(h0.w) + bf2f(h1.w) + bf2f(h2.w) + bf2f(h3.w);
        }
        for (; j < p1; ++j) {
            ushort4 h0 = *(const ushort4*)(base + (size_t)adj[j] * F);
            a0 += bf2f(h0.x); a1 += bf2f(h0.y); a2 += bf2f(h0.z); a3 += bf2f(h0.w);
        }
        ushort4 o = make_ushort4(f2bf(a0 * d), f2bf(a1 * d), f2bf(a2 * d), f2bf(a3 * d));
        *(ushort4*)(out + (size_t)node * F + lane * 4) = o;
    } else {
        float a0 = 0.f, a1 = 0.f;
        int j = p0;
        for (; j + 3 < p1; j += 4) {
            int s0 = adj[j], s1 = adj[j + 1], s2 = adj[j + 2], s3 = adj[j + 3];
            ushort2 h0 = *(const ushort2*)(base + (size_t)s0 * F);
            ushort2 h1 = *(const ushort2*)(base + (size_t)s1 * F);
            ushort2 h2 = *(const ushort2*)(base + (size_t)s2 * F);
            ushort2 h3 = *(const ushort2*)(base + (size_t)s3 * F);
            a0 += bf2f(h0.x) + bf2f(h1.x) + bf2f(h2.x) + bf2f(h3.x);
            a1 += bf2f(h0.y) + bf2f(h1.y) + bf2f(h2.y) + bf2f(h3.y);
        }
        for (; j < p1; ++j) {
            ushort2 h0 = *(const ushort2*)(base + (size_t)adj[j] * F);
            a0 += bf2f(h0.x); a1 += bf2f(h0.y);
        }
        ushort2 o; o.x = f2bf(a0 * d); o.y = f2bf(a1 * d);
        *(ushort2*)(out + (size_t)node * F + lane * 2) = o;
    }
}

// ---------- GEMM: C[M,256] = A1[:, :K1] ++ A2[:, :K2] times W (Wt is [256][K] bf16) ----------
__global__ __launch_bounds__(256) void k_gemm(
    const u16* __restrict__ A1, int K1,
    const u16* __restrict__ A2, int K2,
    const u16* __restrict__ Wt,
    u16* __restrict__ C, int M) {
    const int K = K1 + K2;
    __shared__ __align__(16) u16 Al[128 * 40];
    __shared__ __align__(16) u16 Bl[128 * 40];
    const int t = threadIdx.x;
    const int lane = t & 63;
    const int wave = t >> 6;
    const int wr = (wave >> 1) * 64, wc = (wave & 1) * 64;
    const int quad = lane >> 4, l15 = lane & 15;
    const int rowBase = blockIdx.x * 128;
    const int colBase = blockIdx.y * 128;

    floatx4 acc[4][4];
#pragma unroll
    for (int i = 0; i < 4; ++i)
#pragma unroll
        for (int j = 0; j < 4; ++j)
            acc[i][j] = (floatx4){0.f, 0.f, 0.f, 0.f};

    const int r0 = t >> 2;             // 0..63
    const int ch0 = (t & 3) * 8;       // 0,8,16,24 (elements)

    for (int kt = 0; kt < K; kt += 32) {
        const u16* As; int lda, kloc;
        if (kt < K1) { As = A1; lda = K1; kloc = kt; }
        else         { As = A2; lda = K2; kloc = kt - K1; }
#pragma unroll
        for (int l = 0; l < 2; ++l) {
            const int r = r0 + l * 64;
            const int grow = rowBase + r;
            uint4 va = make_uint4(0u, 0u, 0u, 0u);
            if (grow < M) va = *(const uint4*)(As + (size_t)grow * lda + (kloc + ch0));
            *(uint4*)(Al + r * 40 + ch0) = va;
            uint4 vb = *(const uint4*)(Wt + (size_t)(colBase + r) * K + (kt + ch0));
            *(uint4*)(Bl + r * 40 + ch0) = vb;
        }
        __syncthreads();
        short8 af[4], bfr[4];
#pragma unroll
        for (int i = 0; i < 4; ++i) af[i] = *(const short8*)(Al + (wr + i * 16 + l15) * 40 + quad * 8);
#pragma unroll
        for (int j = 0; j < 4; ++j) bfr[j] = *(const short8*)(Bl + (wc + j * 16 + l15) * 40 + quad * 8);
#pragma unroll
        for (int i = 0; i < 4; ++i)
#pragma unroll
            for (int j = 0; j < 4; ++j)
                acc[i][j] = __builtin_amdgcn_mfma_f32_16x16x32_bf16(af[i], bfr[j], acc[i][j], 0, 0, 0);
        __syncthreads();
    }
#pragma unroll
    for (int i = 0; i < 4; ++i) {
#pragma unroll
        for (int r = 0; r < 4; ++r) {
            const int row = rowBase + wr + i * 16 + quad * 4 + r;
            if (row < M) {
#pragma unroll
                for (int j = 0; j < 4; ++j) {
                    const int col = colBase + wc + j * 16 + l15;
                    C[(size_t)row * HDIM + col] = f2bf(acc[i][j][r]);
                }
            }
        }
    }
}

// ---------- column stats (sum, sumsq) ----------
__global__ void k_colstats(const u16* __restrict__ Cb, float* __restrict__ stats, int M) {
    const int c = threadIdx.x;
    const int rpb = (M + gridDim.x - 1) / gridDim.x;
    int r0 = blockIdx.x * rpb;
    int r1 = r0 + rpb; if (r1 > M) r1 = M;
    float s = 0.f, ss = 0.f;
    for (int r = r0; r < r1; ++r) {
        float v = bf2f(Cb[(size_t)r * HDIM + c]);
        s += v; ss += v * v;
    }
    atomicAdd(&stats[c], s);
    atomicAdd(&stats[HDIM + c], ss);
}

__global__ void k_bnscale(const float* __restrict__ stats, const float* __restrict__ g,
                          const float* __restrict__ beta, float* __restrict__ sc,
                          float* __restrict__ sh, float invN) {
    int c = threadIdx.x;
    float mu = stats[c] * invN;
    float var = stats[HDIM + c] * invN - mu * mu;
    float s = g[c] * rsqrtf(var + 1e-5f);
    sc[c] = s;
    sh[c] = beta[c] - mu * s;
}

// ---------- h_next = relu(C*scale+shift) + identity (+res_b) ----------
__global__ void k_finalize(const u16* __restrict__ Cb, const u16* __restrict__ iden,
                           const float* __restrict__ sc, const float* __restrict__ sh,
                           const float* __restrict__ resb,
                           u16* __restrict__ hout, int n8) {
    int i = blockIdx.x * 256 + threadIdx.x;
    if (i >= n8) return;
    const int c0 = (i * 8) & (HDIM - 1);
    const ushort4* cp = (const ushort4*)Cb;
    const ushort4* ip = (const ushort4*)iden;
    ushort4 cv0 = cp[2 * i], cv1 = cp[2 * i + 1];
    ushort4 iv0 = ip[2 * i], iv1 = ip[2 * i + 1];
    u16 cc[8] = {cv0.x, cv0.y, cv0.z, cv0.w, cv1.x, cv1.y, cv1.z, cv1.w};
    u16 dd[8] = {iv0.x, iv0.y, iv0.z, iv0.w, iv1.x, iv1.y, iv1.z, iv1.w};
    u16 oo[8];
#pragma unroll
    for (int e = 0; e < 8; ++e) {
        const int c = c0 + e;
        float v = bf2f(cc[e]) * sc[c] + sh[c];
        v = fmaxf(v, 0.f) + bf2f(dd[e]);
        if (resb) v += resb[c];
        oo[e] = f2bf(v);
    }
    ushort4* op = (ushort4*)hout;
    op[2 * i]     = make_ushort4(oo[0], oo[1], oo[2], oo[3]);
    op[2 * i + 1] = make_ushort4(oo[4], oo[5], oo[6], oo[7]);
}

// ---------- readout stage 1: per-node dot(h, lin_W) -> nodedot (no atomics) ----------
__global__ void k_dot(const u16* __restrict__ h, const float* __restrict__ w,
                      float* __restrict__ nodedot, int n) {
    int lane = threadIdx.x & 63;
    int node = blockIdx.x * 4 + (threadIdx.x >> 6);
    if (node >= n) return;
    ushort4 hv = *(const ushort4*)(h + (size_t)node * HDIM + lane * 4);
    float4 wv = *(const float4*)(w + lane * 4);
    float s = bf2f(hv.x) * wv.x + bf2f(hv.y) * wv.y + bf2f(hv.z) * wv.z + bf2f(hv.w) * wv.w;
#pragma unroll
    for (int off = 32; off > 0; off >>= 1) s += __shfl_down(s, off);
    if (lane == 0) nodedot[node] = s;
}

// ---------- graph ptr: exclusive scan of per-graph node counts (256, one block) ----------
__global__ void k_gptr(const int* __restrict__ cntb, int* __restrict__ gptr) {
    __shared__ int ts[256];
    int t = threadIdx.x;
    int v = cntb[t];
    ts[t] = v;
    __syncthreads();
    for (int off = 1; off < 256; off <<= 1) {
        int u = (t >= off) ? ts[t - off] : 0;
        __syncthreads();
        ts[t] += u;
        __syncthreads();
    }
    if (t == 0) gptr[0] = 0;
    gptr[t + 1] = ts[t];  // inclusive -> shifted = exclusive boundaries
}

// ---------- readout stage 2: one block per graph, contiguous segment sum ----------
__global__ void k_pool(const float* __restrict__ nodedot, const int* __restrict__ gptr,
                       const float* __restrict__ lb, float* __restrict__ out) {
    const int g = blockIdx.x;
    const int r0 = gptr[g], r1 = gptr[g + 1];
    float s = 0.f;
    for (int i = r0 + threadIdx.x; i < r1; i += 256) s += nodedot[i];
#pragma unroll
    for (int off = 32; off > 0; off >>= 1) s += __shfl_down(s, off);
    __shared__ float red[4];
    const int wave = threadIdx.x >> 6;
    if ((threadIdx.x & 63) == 0) red[wave] = s;
    __syncthreads();
    if (threadIdx.x == 0) {
        float tot = red[0] + red[1] + red[2] + red[3];
        int c = r1 - r0; if (c < 1) c = 1;
        out[g] = tot / (float)c + lb[0];
    }
}

extern "C" void kernel_launch(void* const* d_in, const int* in_sizes, int n_in,
                              void* d_out, int out_size, void* d_ws, size_t ws_size,
                              hipStream_t stream) {
    const float* x     = (const float*)d_in[0];
    const int*   ei    = (const int*)d_in[1];
    const int*   batch = (const int*)d_in[2];
    const float* Wl1 = (const float*)d_in[3];
    const float* Wr1 = (const float*)d_in[5];
    const float* g1  = (const float*)d_in[6];
    const float* be1 = (const float*)d_in[7];
    const float* Wl2 = (const float*)d_in[8];
    const float* Wr2 = (const float*)d_in[10];
    const float* g2  = (const float*)d_in[11];
    const float* be2 = (const float*)d_in[12];
    const float* Wl3 = (const float*)d_in[13];
    const float* Wr3 = (const float*)d_in[15];
    const float* g3  = (const float*)d_in[16];
    const float* be3 = (const float*)d_in[17];
    const float* Wl4 = (const float*)d_in[18];
    const float* Wr4 = (const float*)d_in[20];
    const float* g4  = (const float*)d_in[21];
    const float* be4 = (const float*)d_in[22];
    const float* resW = (const float*)d_in[23];
    const float* resb = (const float*)d_in[24];
    const float* linW = (const float*)d_in[25];
    const float* linb = (const float*)d_in[26];
    float* out = (float*)d_out;

    char* p = (char*)d_ws;
    auto carve = [&](size_t bytes) -> char* {
        char* r = p;
        p += (bytes + 255) & ~(size_t)255;
        return r;
    };
    int*   cptr   = (int*)carve((size_t)(N_NODESC + 1) * 4);
    int*   counts = (int*)carve((size_t)N_NODESC * 4);
    int*   fillc  = (int*)carve((size_t)N_NODESC * 4);
    float* dinv   = (float*)carve((size_t)N_NODESC * 4);
    int*   cntb   = (int*)carve(N_GRAPHSC * 4);
    int*   gptr   = (int*)carve((N_GRAPHSC + 1) * 4);
    float* nodedot= (float*)carve((size_t)N_NODESC * 4);
    float* stats  = (float*)carve(4 * 512 * 4);
    float* scale  = (float*)carve(256 * 4);
    float* shift  = (float*)carve(256 * 4);
    int*   bsum   = (int*)carve(SCAN_NB * 4);
    int*   boff   = (int*)carve(SCAN_NB * 4);
    int*   adj    = (int*)carve((size_t)N_EDGESC * 4);
    u16*   Wt1    = (u16*)carve(256 * 256 * 2);
    u16*   Wt2    = (u16*)carve(256 * 512 * 2);
    u16*   Wt3    = (u16*)carve(256 * 512 * 2);
    u16*   Wt4    = (u16*)carve(256 * 512 * 2);
    u16*   Rt     = (u16*)carve(256 * 128 * 2);
    u16*   xb     = (u16*)carve((size_t)N_NODESC * F_INC * 2);
    u16*   hA     = (u16*)carve((size_t)N_NODESC * HDIM * 2);
    u16*   hB     = (u16*)carve((size_t)N_NODESC * HDIM * 2);
    u16*   agg    = (u16*)carve((size_t)N_NODESC * HDIM * 2);  // aliased as res for layer 1
    u16*   Cb     = (u16*)carve((size_t)N_NODESC * HDIM * 2);

    hipMemsetAsync(counts, 0, (size_t)N_NODESC * 4, stream);
    hipMemsetAsync(fillc, 0, (size_t)N_NODESC * 4, stream);
    hipMemsetAsync(cntb, 0, N_GRAPHSC * 4, stream);
    hipMemsetAsync(stats, 0, 4 * 512 * 4, stream);

    const int* srcp = ei;
    const int* dstp = ei + N_EDGESC;

    // weight prep + x conversion
    k_wcat<<<(256 * 256 + 255) / 256, 256, 0, stream>>>(Wl1, Wr1, 128, 128, Wt1);
    k_wcat<<<(256 * 512 + 255) / 256, 256, 0, stream>>>(Wl2, Wr2, 256, 256, Wt2);
    k_wcat<<<(256 * 512 + 255) / 256, 256, 0, stream>>>(Wl3, Wr3, 256, 256, Wt3);
    k_wcat<<<(256 * 512 + 255) / 256, 256, 0, stream>>>(Wl4, Wr4, 256, 256, Wt4);
    k_wcat<<<(256 * 128 + 255) / 256, 256, 0, stream>>>(resW, resW, 128, 0, Rt);
    k_f2bf4<<<(N_NODESC * F_INC / 4 + 255) / 256, 256, 0, stream>>>(x, xb, N_NODESC * F_INC / 4);

    // graph structure
    k_count<<<(N_EDGESC + 255) / 256, 256, 0, stream>>>(dstp, counts, N_EDGESC);
    k_count<<<(N_NODESC + 255) / 256, 256, 0, stream>>>(batch, cntb, N_NODESC);
    k_gptr<<<1, 256, 0, stream>>>(cntb, gptr);
    k_scan_bsum<<<SCAN_NB, 256, 0, stream>>>(counts, bsum, N_NODESC);
    k_scan_boff<<<1, 256, 0, stream>>>(bsum, boff, SCAN_NB);
    k_scan_write<<<SCAN_NB, 256, 0, stream>>>(counts, boff, cptr, N_NODESC);
    k_deginv<<<(N_NODESC + 255) / 256, 256, 0, stream>>>(counts, dinv, N_NODESC);
    k_fill<<<(N_EDGESC + 255) / 256, 256, 0, stream>>>(srcp, dstp, cptr, fillc, adj, N_EDGESC);

    dim3 gGemm(782, 2);
    const float invN = 1.0f / (float)N_NODESC;
    const int n8 = N_NODESC * HDIM / 8;
    const int finBlocks = (n8 + 255) / 256;

    // ---- layer 1 ----
    k_aggregate<128><<<25000, 256, 0, stream>>>(xb, cptr, adj, dinv, agg, N_NODESC);
    k_gemm<<<gGemm, 256, 0, stream>>>(agg, 128, xb, 128, Wt1, Cb, N_NODESC);
    k_gemm<<<gGemm, 256, 0, stream>>>(xb, 128, xb, 0, Rt, agg, N_NODESC);  // res reuses agg
    k_colstats<<<256, 256, 0, stream>>>(Cb, stats, N_NODESC);
    k_bnscale<<<1, 256, 0, stream>>>(stats, g1, be1, scale, shift, invN);
    k_finalize<<<finBlocks, 256, 0, stream>>>(Cb, agg, scale, shift, resb, hA, n8);

    // ---- layer 2 ----
    k_aggregate<256><<<25000, 256, 0, stream>>>(hA, cptr, adj, dinv, agg, N_NODESC);
    k_gemm<<<gGemm, 256, 0, stream>>>(agg, 256, hA, 256, Wt2, Cb, N_NODESC);
    k_colstats<<<256, 256, 0, stream>>>(Cb, stats + 512, N_NODESC);
    k_bnscale<<<1, 256, 0, stream>>>(stats + 512, g2, be2, scale, shift, invN);
    k_finalize<<<finBlocks, 256, 0, stream>>>(Cb, hA, scale, shift, nullptr, hB, n8);

    // ---- layer 3 ----
    k_aggregate<256><<<25000, 256, 0, stream>>>(hB, cptr, adj, dinv, agg, N_NODESC);
    k_gemm<<<gGemm, 256, 0, stream>>>(agg, 256, hB, 256, Wt3, Cb, N_NODESC);
    k_colstats<<<256, 256, 0, stream>>>(Cb, stats + 1024, N_NODESC);
    k_bnscale<<<1, 256, 0, stream>>>(stats + 1024, g3, be3, scale, shift, invN);
    k_finalize<<<finBlocks, 256, 0, stream>>>(Cb, hB, scale, shift, nullptr, hA, n8);

    // ---- layer 4 ----
    k_aggregate<256><<<25000, 256, 0, stream>>>(hA, cptr, adj, dinv, agg, N_NODESC);
    k_gemm<<<gGemm, 256, 0, stream>>>(agg, 256, hA, 256, Wt4, Cb, N_NODESC);
    k_colstats<<<256, 256, 0, stream>>>(Cb, stats + 1536, N_NODESC);
    k_bnscale<<<1, 256, 0, stream>>>(stats + 1536, g4, be4, scale, shift, invN);
    k_finalize<<<finBlocks, 256, 0, stream>>>(Cb, hA, scale, shift, nullptr, hB, n8);

    // ---- pooled @ lin_W + lin_b  ==  seg_mean(h @ lin_W) + lin_b ----
    k_dot<<<25000, 256, 0, stream>>>(hB, linW, nodedot, N_NODESC);
    k_pool<<<N_GRAPHSC, 256, 0, stream>>>(nodedot, gptr, linb, out);
}

// Round 3
// 1794.409 us; speedup vs baseline: 1.2754x; 1.0915x over previous
//
#include <hip/hip_runtime.h>

typedef unsigned short u16;
typedef __attribute__((ext_vector_type(8))) short short8;
typedef __attribute__((ext_vector_type(4))) float floatx4;

#define N_NODESC 100000
#define N_EDGESC 1600000
#define N_GRAPHSC 256
#define F_INC 128
#define HDIM 256
#define SCAN_CHUNK 512
#define SCAN_NB ((N_NODESC + SCAN_CHUNK - 1) / SCAN_CHUNK)  // 196

__device__ __forceinline__ float bf2f(u16 u) {
    union { unsigned int i; float f; } v; v.i = ((unsigned int)u) << 16; return v.f;
}
__device__ __forceinline__ u16 f2bf(float f) {
    union { float f; unsigned int i; } v; v.f = f;
    unsigned int b = v.i;
    b += 0x7fffu + ((b >> 16) & 1u);
    return (u16)(b >> 16);
}
// XCC_ID hwreg (id=20) — measured working on gfx950 (learn_hip m09)
__device__ __forceinline__ int get_xcd() {
    int x;
    asm volatile("s_getreg_b32 %0, hwreg(20, 0, 4)" : "=s"(x));
    return x & 7;
}

// ---------- weight prep: out[c*K + k] = (k<K1 ? Wl[k][c] : Wr[k-K1][c]) as bf16 ----------
__global__ void k_wcat(const float* __restrict__ Wl, const float* __restrict__ Wr,
                       int K1, int K2, u16* __restrict__ out) {
    int K = K1 + K2;
    int idx = blockIdx.x * 256 + threadIdx.x;
    if (idx >= 256 * K) return;
    int c = idx / K, k = idx - c * K;
    float v = (k < K1) ? Wl[k * 256 + c] : Wr[(k - K1) * 256 + c];
    out[idx] = f2bf(v);
}

// ---------- fp32 -> bf16 vectorized convert ----------
__global__ void k_f2bf4(const float* __restrict__ in, u16* __restrict__ out, int n4) {
    int i = blockIdx.x * 256 + threadIdx.x;
    if (i >= n4) return;
    float4 v = ((const float4*)in)[i];
    ushort4 o = make_ushort4(f2bf(v.x), f2bf(v.y), f2bf(v.z), f2bf(v.w));
    ((ushort4*)out)[i] = o;
}

// ---------- edge count: per-XCD partial histograms, XCD-local (workgroup-scope) atomics ----------
// P[xcd][node]; rank within (xcd,node) returned by the atomic -> packed into epack.
__global__ void k_countP(const int* __restrict__ dst, unsigned int* __restrict__ P,
                         unsigned int* __restrict__ epack, int E) {
    const int xcd = get_xcd();
    unsigned int* Px = P + (size_t)xcd * N_NODESC;
    const int e0 = blockIdx.x * 1024 + threadIdx.x;
#pragma unroll
    for (int l = 0; l < 4; ++l) {
        int e = e0 + l * 256;
        if (e < E) {
            int d = dst[e];
            unsigned int pos = __hip_atomic_fetch_add(&Px[d], 1u, __ATOMIC_RELAXED,
                                                      __HIP_MEMORY_SCOPE_WORKGROUP);
            epack[e] = ((unsigned int)xcd << 16) | pos;
        }
    }
}

// ---------- reduce partials: counts, 1/deg, per-(node,xcd) base offsets ----------
__global__ void k_reduceP(const unsigned int* __restrict__ P, int* __restrict__ counts,
                          float* __restrict__ dinv, u16* __restrict__ Bp, int n) {
    int d = blockIdx.x * 256 + threadIdx.x;
    if (d >= n) return;
    unsigned int s = 0;
    u16 b[8];
#pragma unroll
    for (int x = 0; x < 8; ++x) {
        b[x] = (u16)s;
        s += P[(size_t)x * n + d];
    }
    counts[d] = (int)s;
    dinv[d] = 1.0f / (float)(s > 1u ? s : 1u);
    ushort4* bp = (ushort4*)(Bp + (size_t)d * 8);
    bp[0] = make_ushort4(b[0], b[1], b[2], b[3]);
    bp[1] = make_ushort4(b[4], b[5], b[6], b[7]);
}

// ---------- 3-phase scan over counts -> csr_ptr ----------
__global__ void k_scan_bsum(const int* __restrict__ cnt, int* __restrict__ bsum, int n) {
    __shared__ int ts[256];
    int t = threadIdx.x;
    int i0 = blockIdx.x * SCAN_CHUNK + t * 2;
    int c0 = (i0 < n) ? cnt[i0] : 0;
    int c1 = (i0 + 1 < n) ? cnt[i0 + 1] : 0;
    ts[t] = c0 + c1;
    __syncthreads();
    for (int off = 128; off > 0; off >>= 1) {
        if (t < off) ts[t] += ts[t + off];
        __syncthreads();
    }
    if (t == 0) bsum[blockIdx.x] = ts[0];
}

__global__ void k_scan_boff(const int* __restrict__ bsum, int* __restrict__ boff, int nb) {
    __shared__ int ts[256];
    int t = threadIdx.x;
    int v = (t < nb) ? bsum[t] : 0;
    ts[t] = v;
    __syncthreads();
    for (int off = 1; off < 256; off <<= 1) {
        int u = (t >= off) ? ts[t - off] : 0;
        __syncthreads();
        ts[t] += u;
        __syncthreads();
    }
    if (t < nb) boff[t] = ts[t] - v;  // exclusive
}

__global__ void k_scan_write(const int* __restrict__ cnt, const int* __restrict__ boff,
                             int* __restrict__ cptr, int n) {
    __shared__ int ts[256];
    int t = threadIdx.x;
    int i0 = blockIdx.x * SCAN_CHUNK + t * 2;
    int c0 = (i0 < n) ? cnt[i0] : 0;
    int c1 = (i0 + 1 < n) ? cnt[i0 + 1] : 0;
    int ms = c0 + c1;
    ts[t] = ms;
    __syncthreads();
    for (int off = 1; off < 256; off <<= 1) {
        int u = (t >= off) ? ts[t - off] : 0;
        __syncthreads();
        ts[t] += u;
        __syncthreads();
    }
    int excl = ts[t] - ms + boff[blockIdx.x];
    if (i0 < n) cptr[i0] = excl;
    if (i0 + 1 < n) cptr[i0 + 1] = excl + c0;
    if (i0 == n - 1) cptr[n] = excl + c0;
    else if (i0 + 1 == n - 1) cptr[n] = excl + c0 + c1;
}

// ---------- CSR fill: slot fully determined, zero atomics ----------
__global__ void k_fill2(const int* __restrict__ src, const int* __restrict__ dst,
                        const unsigned int* __restrict__ epack,
                        const int* __restrict__ cptr, const u16* __restrict__ Bp,
                        int* __restrict__ adj, int E) {
    const int e0 = blockIdx.x * 1024 + threadIdx.x;
#pragma unroll
    for (int l = 0; l < 4; ++l) {
        int e = e0 + l * 256;
        if (e < E) {
            int d = dst[e];
            unsigned int pk = epack[e];
            int x = (int)(pk >> 16);
            int pos = (int)(pk & 0xFFFFu);
            adj[cptr[d] + (int)Bp[(size_t)d * 8 + x] + pos] = src[e];
        }
    }
}

// ---------- graph ranges: batch is sorted -> binary search lower bounds ----------
__global__ void k_gfind(const int* __restrict__ batch, int* __restrict__ gptr, int n) {
    int g = blockIdx.x * 64 + threadIdx.x;
    if (g > N_GRAPHSC) return;
    int lo = 0, hi = n;
    while (lo < hi) {
        int mid = (lo + hi) >> 1;
        if (batch[mid] < g) lo = mid + 1; else hi = mid;
    }
    gptr[g] = lo;
}

// ---------- aggregation: one wave per node, lane holds F/64 features ----------
template <int F>
__global__ void k_aggregate(const u16* __restrict__ hin, const int* __restrict__ cptr,
                            const int* __restrict__ adj, const float* __restrict__ di,
                            u16* __restrict__ out, int n) {
    constexpr int V = F / 64;
    int lane = threadIdx.x & 63;
    int node = blockIdx.x * 4 + (threadIdx.x >> 6);
    if (node >= n) return;
    int p0 = cptr[node], p1 = cptr[node + 1];
    const u16* base = hin + (size_t)lane * V;
    float d = di[node];
    if constexpr (V == 4) {
        float a0 = 0.f, a1 = 0.f, a2 = 0.f, a3 = 0.f;
        int j = p0;
        for (; j + 3 < p1; j += 4) {
            int s0 = adj[j], s1 = adj[j + 1], s2 = adj[j + 2], s3 = adj[j + 3];
            ushort4 h0 = *(const ushort4*)(base + (size_t)s0 * F);
            ushort4 h1 = *(const ushort4*)(base + (size_t)s1 * F);
            ushort4 h2 = *(const ushort4*)(base + (size_t)s2 * F);
            ushort4 h3 = *(const ushort4*)(base + (size_t)s3 * F);
            a0 += bf2f(h0.x) + bf2f(h1.x) + bf2f(h2.x) + bf2f(h3.x);
            a1 += bf2f(h0.y) + bf2f(h1.y) + bf2f(h2.y) + bf2f(h3.y);
            a2 += bf2f(h0.z) + bf2f(h1.z) + bf2f(h2.z) + bf2f(h3.z);
            a3 += bf2f(h0.w) + bf2f(h1.w) + bf2f(h2.w) + bf2f(h3.w);
        }
        for (; j < p1; ++j) {
            ushort4 h0 = *(const ushort4*)(base + (size_t)adj[j] * F);
            a0 += bf2f(h0.x); a1 += bf2f(h0.y); a2 += bf2f(h0.z); a3 += bf2f(h0.w);
        }
        ushort4 o = make_ushort4(f2bf(a0 * d), f2bf(a1 * d), f2bf(a2 * d), f2bf(a3 * d));
        *(ushort4*)(out + (size_t)node * F + lane * 4) = o;
    } else {
        float a0 = 0.f, a1 = 0.f;
        int j = p0;
        for (; j + 3 < p1; j += 4) {
            int s0 = adj[j], s1 = adj[j + 1], s2 = adj[j + 2], s3 = adj[j + 3];
            ushort2 h0 = *(const ushort2*)(base + (size_t)s0 * F);
            ushort2 h1 = *(const ushort2*)(base + (size_t)s1 * F);
            ushort2 h2 = *(const ushort2*)(base + (size_t)s2 * F);
            ushort2 h3 = *(const ushort2*)(base + (size_t)s3 * F);
            a0 += bf2f(h0.x) + bf2f(h1.x) + bf2f(h2.x) + bf2f(h3.x);
            a1 += bf2f(h0.y) + bf2f(h1.y) + bf2f(h2.y) + bf2f(h3.y);
        }
        for (; j < p1; ++j) {
            ushort2 h0 = *(const ushort2*)(base + (size_t)adj[j] * F);
            a0 += bf2f(h0.x); a1 += bf2f(h0.y);
        }
        ushort2 o; o.x = f2bf(a0 * d); o.y = f2bf(a1 * d);
        *(ushort2*)(out + (size_t)node * F + lane * 2) = o;
    }
}

// ---------- GEMM: C[M,256] = A1[:, :K1] ++ A2[:, :K2] times W (Wt is [256][K] bf16) ----------
__global__ __launch_bounds__(256) void k_gemm(
    const u16* __restrict__ A1, int K1,
    const u16* __restrict__ A2, int K2,
    const u16* __restrict__ Wt,
    u16* __restrict__ C, int M) {
    const int K = K1 + K2;
    __shared__ __align__(16) u16 Al[128 * 40];
    __shared__ __align__(16) u16 Bl[128 * 40];
    const int t = threadIdx.x;
    const int lane = t & 63;
    const int wave = t >> 6;
    const int wr = (wave >> 1) * 64, wc = (wave & 1) * 64;
    const int quad = lane >> 4, l15 = lane & 15;
    const int rowBase = blockIdx.x * 128;
    const int colBase = blockIdx.y * 128;

    floatx4 acc[4][4];
#pragma unroll
    for (int i = 0; i < 4; ++i)
#pragma unroll
        for (int j = 0; j < 4; ++j)
            acc[i][j] = (floatx4){0.f, 0.f, 0.f, 0.f};

    const int r0 = t >> 2;             // 0..63
    const int ch0 = (t & 3) * 8;       // 0,8,16,24 (elements)

    for (int kt = 0; kt < K; kt += 32) {
        const u16* As; int lda, kloc;
        if (kt < K1) { As = A1; lda = K1; kloc = kt; }
        else         { As = A2; lda = K2; kloc = kt - K1; }
#pragma unroll
        for (int l = 0; l < 2; ++l) {
            const int r = r0 + l * 64;
            const int grow = rowBase + r;
            uint4 va = make_uint4(0u, 0u, 0u, 0u);
            if (grow < M) va = *(const uint4*)(As + (size_t)grow * lda + (kloc + ch0));
            *(uint4*)(Al + r * 40 + ch0) = va;
            uint4 vb = *(const uint4*)(Wt + (size_t)(colBase + r) * K + (kt + ch0));
            *(uint4*)(Bl + r * 40 + ch0) = vb;
        }
        __syncthreads();
        short8 af[4], bfr[4];
#pragma unroll
        for (int i = 0; i < 4; ++i) af[i] = *(const short8*)(Al + (wr + i * 16 + l15) * 40 + quad * 8);
#pragma unroll
        for (int j = 0; j < 4; ++j) bfr[j] = *(const short8*)(Bl + (wc + j * 16 + l15) * 40 + quad * 8);
#pragma unroll
        for (int i = 0; i < 4; ++i)
#pragma unroll
            for (int j = 0; j < 4; ++j)
                acc[i][j] = __builtin_amdgcn_mfma_f32_16x16x32_bf16(af[i], bfr[j], acc[i][j], 0, 0, 0);
        __syncthreads();
    }
#pragma unroll
    for (int i = 0; i < 4; ++i) {
#pragma unroll
        for (int r = 0; r < 4; ++r) {
            const int row = rowBase + wr + i * 16 + quad * 4 + r;
            if (row < M) {
#pragma unroll
                for (int j = 0; j < 4; ++j) {
                    const int col = colBase + wc + j * 16 + l15;
                    C[(size_t)row * HDIM + col] = f2bf(acc[i][j][r]);
                }
            }
        }
    }
}

// ---------- column stats (sum, sumsq) ----------
__global__ void k_colstats(const u16* __restrict__ Cb, float* __restrict__ stats, int M) {
    const int c = threadIdx.x;
    const int rpb = (M + gridDim.x - 1) / gridDim.x;
    int r0 = blockIdx.x * rpb;
    int r1 = r0 + rpb; if (r1 > M) r1 = M;
    float s = 0.f, ss = 0.f;
    for (int r = r0; r < r1; ++r) {
        float v = bf2f(Cb[(size_t)r * HDIM + c]);
        s += v; ss += v * v;
    }
    atomicAdd(&stats[c], s);
    atomicAdd(&stats[HDIM + c], ss);
}

__global__ void k_bnscale(const float* __restrict__ stats, const float* __restrict__ g,
                          const float* __restrict__ beta, float* __restrict__ sc,
                          float* __restrict__ sh, float invN) {
    int c = threadIdx.x;
    float mu = stats[c] * invN;
    float var = stats[HDIM + c] * invN - mu * mu;
    float s = g[c] * rsqrtf(var + 1e-5f);
    sc[c] = s;
    sh[c] = beta[c] - mu * s;
}

// ---------- h_next = relu(C*scale+shift) + identity (+res_b) ----------
__global__ void k_finalize(const u16* __restrict__ Cb, const u16* __restrict__ iden,
                           const float* __restrict__ sc, const float* __restrict__ sh,
                           const float* __restrict__ resb,
                           u16* __restrict__ hout, int n8) {
    int i = blockIdx.x * 256 + threadIdx.x;
    if (i >= n8) return;
    const int c0 = (i * 8) & (HDIM - 1);
    const ushort4* cp = (const ushort4*)Cb;
    const ushort4* ip = (const ushort4*)iden;
    ushort4 cv0 = cp[2 * i], cv1 = cp[2 * i + 1];
    ushort4 iv0 = ip[2 * i], iv1 = ip[2 * i + 1];
    u16 cc[8] = {cv0.x, cv0.y, cv0.z, cv0.w, cv1.x, cv1.y, cv1.z, cv1.w};
    u16 dd[8] = {iv0.x, iv0.y, iv0.z, iv0.w, iv1.x, iv1.y, iv1.z, iv1.w};
    u16 oo[8];
#pragma unroll
    for (int e = 0; e < 8; ++e) {
        const int c = c0 + e;
        float v = bf2f(cc[e]) * sc[c] + sh[c];
        v = fmaxf(v, 0.f) + bf2f(dd[e]);
        if (resb) v += resb[c];
        oo[e] = f2bf(v);
    }
    ushort4* op = (ushort4*)hout;
    op[2 * i]     = make_ushort4(oo[0], oo[1], oo[2], oo[3]);
    op[2 * i + 1] = make_ushort4(oo[4], oo[5], oo[6], oo[7]);
}

// ---------- readout stage 1: per-node dot(h, lin_W) -> nodedot (no atomics) ----------
__global__ void k_dot(const u16* __restrict__ h, const float* __restrict__ w,
                      float* __restrict__ nodedot, int n) {
    int lane = threadIdx.x & 63;
    int node = blockIdx.x * 4 + (threadIdx.x >> 6);
    if (node >= n) return;
    ushort4 hv = *(const ushort4*)(h + (size_t)node * HDIM + lane * 4);
    float4 wv = *(const float4*)(w + lane * 4);
    float s = bf2f(hv.x) * wv.x + bf2f(hv.y) * wv.y + bf2f(hv.z) * wv.z + bf2f(hv.w) * wv.w;
#pragma unroll
    for (int off = 32; off > 0; off >>= 1) s += __shfl_down(s, off);
    if (lane == 0) nodedot[node] = s;
}

// ---------- readout stage 2: one block per graph, contiguous segment sum ----------
__global__ void k_pool(const float* __restrict__ nodedot, const int* __restrict__ gptr,
                       const float* __restrict__ lb, float* __restrict__ out) {
    const int g = blockIdx.x;
    const int r0 = gptr[g], r1 = gptr[g + 1];
    float s = 0.f;
    for (int i = r0 + threadIdx.x; i < r1; i += 256) s += nodedot[i];
#pragma unroll
    for (int off = 32; off > 0; off >>= 1) s += __shfl_down(s, off);
    __shared__ float red[4];
    const int wave = threadIdx.x >> 6;
    if ((threadIdx.x & 63) == 0) red[wave] = s;
    __syncthreads();
    if (threadIdx.x == 0) {
        float tot = red[0] + red[1] + red[2] + red[3];
        int c = r1 - r0; if (c < 1) c = 1;
        out[g] = tot / (float)c + lb[0];
    }
}

extern "C" void kernel_launch(void* const* d_in, const int* in_sizes, int n_in,
                              void* d_out, int out_size, void* d_ws, size_t ws_size,
                              hipStream_t stream) {
    const float* x     = (const float*)d_in[0];
    const int*   ei    = (const int*)d_in[1];
    const int*   batch = (const int*)d_in[2];
    const float* Wl1 = (const float*)d_in[3];
    const float* Wr1 = (const float*)d_in[5];
    const float* g1  = (const float*)d_in[6];
    const float* be1 = (const float*)d_in[7];
    const float* Wl2 = (const float*)d_in[8];
    const float* Wr2 = (const float*)d_in[10];
    const float* g2  = (const float*)d_in[11];
    const float* be2 = (const float*)d_in[12];
    const float* Wl3 = (const float*)d_in[13];
    const float* Wr3 = (const float*)d_in[15];
    const float* g3  = (const float*)d_in[16];
    const float* be3 = (const float*)d_in[17];
    const float* Wl4 = (const float*)d_in[18];
    const float* Wr4 = (const float*)d_in[20];
    const float* g4  = (const float*)d_in[21];
    const float* be4 = (const float*)d_in[22];
    const float* resW = (const float*)d_in[23];
    const float* resb = (const float*)d_in[24];
    const float* linW = (const float*)d_in[25];
    const float* linb = (const float*)d_in[26];
    float* out = (float*)d_out;

    char* p = (char*)d_ws;
    auto carve = [&](size_t bytes) -> char* {
        char* r = p;
        p += (bytes + 255) & ~(size_t)255;
        return r;
    };
    int*   cptr   = (int*)carve((size_t)(N_NODESC + 1) * 4);
    int*   counts = (int*)carve((size_t)N_NODESC * 4);
    float* dinv   = (float*)carve((size_t)N_NODESC * 4);
    int*   gptr   = (int*)carve((N_GRAPHSC + 1) * 4);
    float* nodedot= (float*)carve((size_t)N_NODESC * 4);
    float* stats  = (float*)carve(4 * 512 * 4);
    float* scale  = (float*)carve(256 * 4);
    float* shift  = (float*)carve(256 * 4);
    int*   bsum   = (int*)carve(SCAN_NB * 4);
    int*   boff   = (int*)carve(SCAN_NB * 4);
    int*   adj    = (int*)carve((size_t)N_EDGESC * 4);
    u16*   Wt1    = (u16*)carve(256 * 256 * 2);
    u16*   Wt2    = (u16*)carve(256 * 512 * 2);
    u16*   Wt3    = (u16*)carve(256 * 512 * 2);
    u16*   Wt4    = (u16*)carve(256 * 512 * 2);
    u16*   Rt     = (u16*)carve(256 * 128 * 2);
    u16*   xb     = (u16*)carve((size_t)N_NODESC * F_INC * 2);
    u16*   hA     = (u16*)carve((size_t)N_NODESC * HDIM * 2);
    u16*   hB     = (u16*)carve((size_t)N_NODESC * HDIM * 2);
    u16*   agg    = (u16*)carve((size_t)N_NODESC * HDIM * 2);  // aliased as res for layer 1
    u16*   Cb     = (u16*)carve((size_t)N_NODESC * HDIM * 2);

    // CSR-build temporaries alias big buffers that are dead during the build:
    unsigned int* P     = (unsigned int*)hA;  // 8*100K u32 = 3.2 MB; dead before hA written (layer-1 finalize)
    unsigned int* epack = (unsigned int*)Cb;  // 1.6M u32 = 6.4 MB; dead before Cb written (layer-1 gemm)
    u16*          Bp    = (u16*)hB;           // 100K*8 u16 = 1.6 MB; dead before hB written (layer-2 finalize)

    hipMemsetAsync(P, 0, (size_t)8 * N_NODESC * 4, stream);
    hipMemsetAsync(stats, 0, 4 * 512 * 4, stream);

    const int* srcp = ei;
    const int* dstp = ei + N_EDGESC;

    // weight prep + x conversion
    k_wcat<<<(256 * 256 + 255) / 256, 256, 0, stream>>>(Wl1, Wr1, 128, 128, Wt1);
    k_wcat<<<(256 * 512 + 255) / 256, 256, 0, stream>>>(Wl2, Wr2, 256, 256, Wt2);
    k_wcat<<<(256 * 512 + 255) / 256, 256, 0, stream>>>(Wl3, Wr3, 256, 256, Wt3);
    k_wcat<<<(256 * 512 + 255) / 256, 256, 0, stream>>>(Wl4, Wr4, 256, 256, Wt4);
    k_wcat<<<(256 * 128 + 255) / 256, 256, 0, stream>>>(resW, resW, 128, 0, Rt);
    k_f2bf4<<<(N_NODESC * F_INC / 4 + 255) / 256, 256, 0, stream>>>(x, xb, N_NODESC * F_INC / 4);

    // graph structure (no device-scope atomics anywhere)
    k_gfind<<<5, 64, 0, stream>>>(batch, gptr, N_NODESC);
    k_countP<<<(N_EDGESC + 1023) / 1024, 256, 0, stream>>>(dstp, P, epack, N_EDGESC);
    k_reduceP<<<(N_NODESC + 255) / 256, 256, 0, stream>>>(P, counts, dinv, Bp, N_NODESC);
    k_scan_bsum<<<SCAN_NB, 256, 0, stream>>>(counts, bsum, N_NODESC);
    k_scan_boff<<<1, 256, 0, stream>>>(bsum, boff, SCAN_NB);
    k_scan_write<<<SCAN_NB, 256, 0, stream>>>(counts, boff, cptr, N_NODESC);
    k_fill2<<<(N_EDGESC + 1023) / 1024, 256, 0, stream>>>(srcp, dstp, epack, cptr, Bp, adj, N_EDGESC);

    dim3 gGemm(782, 2);
    const float invN = 1.0f / (float)N_NODESC;
    const int n8 = N_NODESC * HDIM / 8;
    const int finBlocks = (n8 + 255) / 256;

    // ---- layer 1 ----
    k_aggregate<128><<<25000, 256, 0, stream>>>(xb, cptr, adj, dinv, agg, N_NODESC);
    k_gemm<<<gGemm, 256, 0, stream>>>(agg, 128, xb, 128, Wt1, Cb, N_NODESC);
    k_gemm<<<gGemm, 256, 0, stream>>>(xb, 128, xb, 0, Rt, agg, N_NODESC);  // res reuses agg
    k_colstats<<<256, 256, 0, stream>>>(Cb, stats, N_NODESC);
    k_bnscale<<<1, 256, 0, stream>>>(stats, g1, be1, scale, shift, invN);
    k_finalize<<<finBlocks, 256, 0, stream>>>(Cb, agg, scale, shift, resb, hA, n8);

    // ---- layer 2 ----
    k_aggregate<256><<<25000, 256, 0, stream>>>(hA, cptr, adj, dinv, agg, N_NODESC);
    k_gemm<<<gGemm, 256, 0, stream>>>(agg, 256, hA, 256, Wt2, Cb, N_NODESC);
    k_colstats<<<256, 256, 0, stream>>>(Cb, stats + 512, N_NODESC);
    k_bnscale<<<1, 256, 0, stream>>>(stats + 512, g2, be2, scale, shift, invN);
    k_finalize<<<finBlocks, 256, 0, stream>>>(Cb, hA, scale, shift, nullptr, hB, n8);

    // ---- layer 3 ----
    k_aggregate<256><<<25000, 256, 0, stream>>>(hB, cptr, adj, dinv, agg, N_NODESC);
    k_gemm<<<gGemm, 256, 0, stream>>>(agg, 256, hB, 256, Wt3, Cb, N_NODESC);
    k_colstats<<<256, 256, 0, stream>>>(Cb, stats + 1024, N_NODESC);
    k_bnscale<<<1, 256, 0, stream>>>(stats + 1024, g3, be3, scale, shift, invN);
    k_finalize<<<finBlocks, 256, 0, stream>>>(Cb, hB, scale, shift, nullptr, hA, n8);

    // ---- layer 4 ----
    k_aggregate<256><<<25000, 256, 0, stream>>>(hA, cptr, adj, dinv, agg, N_NODESC);
    k_gemm<<<gGemm, 256, 0, stream>>>(agg, 256, hA, 256, Wt4, Cb, N_NODESC);
    k_colstats<<<256, 256, 0, stream>>>(Cb, stats + 1536, N_NODESC);
    k_bnscale<<<1, 256, 0, stream>>>(stats + 1536, g4, be4, scale, shift, invN);
    k_finalize<<<finBlocks, 256, 0, stream>>>(Cb, hA, scale, shift, nullptr, hB, n8);

    // ---- pooled @ lin_W + lin_b  ==  seg_mean(h @ lin_W) + lin_b ----
    k_dot<<<25000, 256, 0, stream>>>(hB, linW, nodedot, N_NODESC);
    k_pool<<<N_GRAPHSC, 256, 0, stream>>>(nodedot, gptr, linb, out);
}

// Round 4
// 1201.260 us; speedup vs baseline: 1.9052x; 1.4938x over previous
//
#include <hip/hip_runtime.h>

typedef unsigned short u16;
typedef __attribute__((ext_vector_type(8))) short short8;
typedef __attribute__((ext_vector_type(4))) float floatx4;

#define N_NODESC 100000
#define N_EDGESC 1600000
#define N_GRAPHSC 256
#define F_INC 128
#define HDIM 256
#define SCAN_CHUNK 512
#define SCAN_NB ((N_NODESC + SCAN_CHUNK - 1) / SCAN_CHUNK)  // 196

__device__ __forceinline__ float bf2f(u16 u) {
    union { unsigned int i; float f; } v; v.i = ((unsigned int)u) << 16; return v.f;
}
__device__ __forceinline__ u16 f2bf(float f) {
    union { float f; unsigned int i; } v; v.f = f;
    unsigned int b = v.i;
    b += 0x7fffu + ((b >> 16) & 1u);
    return (u16)(b >> 16);
}
__device__ __forceinline__ void up8(uint4 v, float* f) {
    f[0] = bf2f((u16)(v.x & 0xffff)); f[1] = bf2f((u16)(v.x >> 16));
    f[2] = bf2f((u16)(v.y & 0xffff)); f[3] = bf2f((u16)(v.y >> 16));
    f[4] = bf2f((u16)(v.z & 0xffff)); f[5] = bf2f((u16)(v.z >> 16));
    f[6] = bf2f((u16)(v.w & 0xffff)); f[7] = bf2f((u16)(v.w >> 16));
}
__device__ __forceinline__ unsigned int pk2(float a, float b) {
    return (unsigned int)f2bf(a) | ((unsigned int)f2bf(b) << 16);
}
// XCC_ID hwreg (id=20) — measured working on gfx950 (learn_hip m09)
__device__ __forceinline__ int get_xcd() {
    int x;
    asm volatile("s_getreg_b32 %0, hwreg(20, 0, 4)" : "=s"(x));
    return x & 7;
}

// ---------- weight prep: out[c*K + k] = (k<K1 ? Wl[k][c] : Wr[k-K1][c]) as bf16 ----------
__global__ void k_wcat(const float* __restrict__ Wl, const float* __restrict__ Wr,
                       int K1, int K2, u16* __restrict__ out) {
    int K = K1 + K2;
    int idx = blockIdx.x * 256 + threadIdx.x;
    if (idx >= 256 * K) return;
    int c = idx / K, k = idx - c * K;
    float v = (k < K1) ? Wl[k * 256 + c] : Wr[(k - K1) * 256 + c];
    out[idx] = f2bf(v);
}

// ---------- fp32 -> bf16 vectorized convert ----------
__global__ void k_f2bf4(const float* __restrict__ in, u16* __restrict__ out, int n4) {
    int i = blockIdx.x * 256 + threadIdx.x;
    if (i >= n4) return;
    float4 v = ((const float4*)in)[i];
    ushort4 o = make_ushort4(f2bf(v.x), f2bf(v.y), f2bf(v.z), f2bf(v.w));
    ((ushort4*)out)[i] = o;
}

// ---------- edge count: per-XCD partial histograms, XCD-local (workgroup-scope) atomics ----------
__global__ void k_countP(const int* __restrict__ dst, unsigned int* __restrict__ P,
                         unsigned int* __restrict__ epack, int E) {
    const int xcd = get_xcd();
    unsigned int* Px = P + (size_t)xcd * N_NODESC;
    const int e0 = blockIdx.x * 1024 + threadIdx.x;
#pragma unroll
    for (int l = 0; l < 4; ++l) {
        int e = e0 + l * 256;
        if (e < E) {
            int d = dst[e];
            unsigned int pos = __hip_atomic_fetch_add(&Px[d], 1u, __ATOMIC_RELAXED,
                                                      __HIP_MEMORY_SCOPE_WORKGROUP);
            epack[e] = ((unsigned int)xcd << 16) | pos;
        }
    }
}

// ---------- reduce partials: counts, 1/deg, per-(node,xcd) base offsets ----------
__global__ void k_reduceP(const unsigned int* __restrict__ P, int* __restrict__ counts,
                          float* __restrict__ dinv, u16* __restrict__ Bp, int n) {
    int d = blockIdx.x * 256 + threadIdx.x;
    if (d >= n) return;
    unsigned int s = 0;
    u16 b[8];
#pragma unroll
    for (int x = 0; x < 8; ++x) {
        b[x] = (u16)s;
        s += P[(size_t)x * n + d];
    }
    counts[d] = (int)s;
    dinv[d] = 1.0f / (float)(s > 1u ? s : 1u);
    ushort4* bp = (ushort4*)(Bp + (size_t)d * 8);
    bp[0] = make_ushort4(b[0], b[1], b[2], b[3]);
    bp[1] = make_ushort4(b[4], b[5], b[6], b[7]);
}

// ---------- 3-phase scan over counts -> csr_ptr ----------
__global__ void k_scan_bsum(const int* __restrict__ cnt, int* __restrict__ bsum, int n) {
    __shared__ int ts[256];
    int t = threadIdx.x;
    int i0 = blockIdx.x * SCAN_CHUNK + t * 2;
    int c0 = (i0 < n) ? cnt[i0] : 0;
    int c1 = (i0 + 1 < n) ? cnt[i0 + 1] : 0;
    ts[t] = c0 + c1;
    __syncthreads();
    for (int off = 128; off > 0; off >>= 1) {
        if (t < off) ts[t] += ts[t + off];
        __syncthreads();
    }
    if (t == 0) bsum[blockIdx.x] = ts[0];
}

__global__ void k_scan_boff(const int* __restrict__ bsum, int* __restrict__ boff, int nb) {
    __shared__ int ts[256];
    int t = threadIdx.x;
    int v = (t < nb) ? bsum[t] : 0;
    ts[t] = v;
    __syncthreads();
    for (int off = 1; off < 256; off <<= 1) {
        int u = (t >= off) ? ts[t - off] : 0;
        __syncthreads();
        ts[t] += u;
        __syncthreads();
    }
    if (t < nb) boff[t] = ts[t] - v;  // exclusive
}

__global__ void k_scan_write(const int* __restrict__ cnt, const int* __restrict__ boff,
                             int* __restrict__ cptr, int n) {
    __shared__ int ts[256];
    int t = threadIdx.x;
    int i0 = blockIdx.x * SCAN_CHUNK + t * 2;
    int c0 = (i0 < n) ? cnt[i0] : 0;
    int c1 = (i0 + 1 < n) ? cnt[i0 + 1] : 0;
    int ms = c0 + c1;
    ts[t] = ms;
    __syncthreads();
    for (int off = 1; off < 256; off <<= 1) {
        int u = (t >= off) ? ts[t - off] : 0;
        __syncthreads();
        ts[t] += u;
        __syncthreads();
    }
    int excl = ts[t] - ms + boff[blockIdx.x];
    if (i0 < n) cptr[i0] = excl;
    if (i0 + 1 < n) cptr[i0 + 1] = excl + c0;
    if (i0 == n - 1) cptr[n] = excl + c0;
    else if (i0 + 1 == n - 1) cptr[n] = excl + c0 + c1;
}

// ---------- CSR fill: slot fully determined, zero atomics ----------
__global__ void k_fill2(const int* __restrict__ src, const int* __restrict__ dst,
                        const unsigned int* __restrict__ epack,
                        const int* __restrict__ cptr, const u16* __restrict__ Bp,
                        int* __restrict__ adj, int E) {
    const int e0 = blockIdx.x * 1024 + threadIdx.x;
#pragma unroll
    for (int l = 0; l < 4; ++l) {
        int e = e0 + l * 256;
        if (e < E) {
            int d = dst[e];
            unsigned int pk = epack[e];
            int x = (int)(pk >> 16);
            int pos = (int)(pk & 0xFFFFu);
            adj[cptr[d] + (int)Bp[(size_t)d * 8 + x] + pos] = src[e];
        }
    }
}

// ---------- graph ranges: batch is sorted -> binary search lower bounds ----------
__global__ void k_gfind(const int* __restrict__ batch, int* __restrict__ gptr, int n) {
    int g = blockIdx.x * 64 + threadIdx.x;
    if (g > N_GRAPHSC) return;
    int lo = 0, hi = n;
    while (lo < hi) {
        int mid = (lo + hi) >> 1;
        if (batch[mid] < g) lo = mid + 1; else hi = mid;
    }
    gptr[g] = lo;
}

// ---------- aggregation: one wave per node, lane holds F/64 features ----------
template <int F>
__global__ void k_aggregate(const u16* __restrict__ hin, const int* __restrict__ cptr,
                            const int* __restrict__ adj, const float* __restrict__ di,
                            u16* __restrict__ out, int n) {
    constexpr int V = F / 64;
    int lane = threadIdx.x & 63;
    int node = blockIdx.x * 4 + (threadIdx.x >> 6);
    if (node >= n) return;
    int p0 = cptr[node], p1 = cptr[node + 1];
    const u16* base = hin + (size_t)lane * V;
    float d = di[node];
    if constexpr (V == 4) {
        float a0 = 0.f, a1 = 0.f, a2 = 0.f, a3 = 0.f;
        int j = p0;
        for (; j + 3 < p1; j += 4) {
            int s0 = adj[j], s1 = adj[j + 1], s2 = adj[j + 2], s3 = adj[j + 3];
            ushort4 h0 = *(const ushort4*)(base + (size_t)s0 * F);
            ushort4 h1 = *(const ushort4*)(base + (size_t)s1 * F);
            ushort4 h2 = *(const ushort4*)(base + (size_t)s2 * F);
            ushort4 h3 = *(const ushort4*)(base + (size_t)s3 * F);
            a0 += bf2f(h0.x) + bf2f(h1.x) + bf2f(h2.x) + bf2f(h3.x);
            a1 += bf2f(h0.y) + bf2f(h1.y) + bf2f(h2.y) + bf2f(h3.y);
            a2 += bf2f(h0.z) + bf2f(h1.z) + bf2f(h2.z) + bf2f(h3.z);
            a3 += bf2f(h0.w) + bf2f(h1.w) + bf2f(h2.w) + bf2f(h3.w);
        }
        for (; j < p1; ++j) {
            ushort4 h0 = *(const ushort4*)(base + (size_t)adj[j] * F);
            a0 += bf2f(h0.x); a1 += bf2f(h0.y); a2 += bf2f(h0.z); a3 += bf2f(h0.w);
        }
        ushort4 o = make_ushort4(f2bf(a0 * d), f2bf(a1 * d), f2bf(a2 * d), f2bf(a3 * d));
        *(ushort4*)(out + (size_t)node * F + lane * 4) = o;
    } else {
        float a0 = 0.f, a1 = 0.f;
        int j = p0;
        for (; j + 3 < p1; j += 4) {
            int s0 = adj[j], s1 = adj[j + 1], s2 = adj[j + 2], s3 = adj[j + 3];
            ushort2 h0 = *(const ushort2*)(base + (size_t)s0 * F);
            ushort2 h1 = *(const ushort2*)(base + (size_t)s1 * F);
            ushort2 h2 = *(const ushort2*)(base + (size_t)s2 * F);
            ushort2 h3 = *(const ushort2*)(base + (size_t)s3 * F);
            a0 += bf2f(h0.x) + bf2f(h1.x) + bf2f(h2.x) + bf2f(h3.x);
            a1 += bf2f(h0.y) + bf2f(h1.y) + bf2f(h2.y) + bf2f(h3.y);
        }
        for (; j < p1; ++j) {
            ushort2 h0 = *(const ushort2*)(base + (size_t)adj[j] * F);
            a0 += bf2f(h0.x); a1 += bf2f(h0.y);
        }
        ushort2 o; o.x = f2bf(a0 * d); o.y = f2bf(a1 * d);
        *(ushort2*)(out + (size_t)node * F + lane * 2) = o;
    }
}

// ---------- GEMM: C[M,256] = A1[:, :K1] ++ A2[:, :K2] times W (Wt is [256][K] bf16) ----------
__global__ __launch_bounds__(256) void k_gemm(
    const u16* __restrict__ A1, int K1,
    const u16* __restrict__ A2, int K2,
    const u16* __restrict__ Wt,
    u16* __restrict__ C, int M) {
    const int K = K1 + K2;
    __shared__ __align__(16) u16 Al[128 * 40];
    __shared__ __align__(16) u16 Bl[128 * 40];
    const int t = threadIdx.x;
    const int lane = t & 63;
    const int wave = t >> 6;
    const int wr = (wave >> 1) * 64, wc = (wave & 1) * 64;
    const int quad = lane >> 4, l15 = lane & 15;
    const int rowBase = blockIdx.x * 128;
    const int colBase = blockIdx.y * 128;

    floatx4 acc[4][4];
#pragma unroll
    for (int i = 0; i < 4; ++i)
#pragma unroll
        for (int j = 0; j < 4; ++j)
            acc[i][j] = (floatx4){0.f, 0.f, 0.f, 0.f};

    const int r0 = t >> 2;             // 0..63
    const int ch0 = (t & 3) * 8;       // 0,8,16,24 (elements)

    for (int kt = 0; kt < K; kt += 32) {
        const u16* As; int lda, kloc;
        if (kt < K1) { As = A1; lda = K1; kloc = kt; }
        else         { As = A2; lda = K2; kloc = kt - K1; }
#pragma unroll
        for (int l = 0; l < 2; ++l) {
            const int r = r0 + l * 64;
            const int grow = rowBase + r;
            uint4 va = make_uint4(0u, 0u, 0u, 0u);
            if (grow < M) va = *(const uint4*)(As + (size_t)grow * lda + (kloc + ch0));
            *(uint4*)(Al + r * 40 + ch0) = va;
            uint4 vb = *(const uint4*)(Wt + (size_t)(colBase + r) * K + (kt + ch0));
            *(uint4*)(Bl + r * 40 + ch0) = vb;
        }
        __syncthreads();
        short8 af[4], bfr[4];
#pragma unroll
        for (int i = 0; i < 4; ++i) af[i] = *(const short8*)(Al + (wr + i * 16 + l15) * 40 + quad * 8);
#pragma unroll
        for (int j = 0; j < 4; ++j) bfr[j] = *(const short8*)(Bl + (wc + j * 16 + l15) * 40 + quad * 8);
#pragma unroll
        for (int i = 0; i < 4; ++i)
#pragma unroll
            for (int j = 0; j < 4; ++j)
                acc[i][j] = __builtin_amdgcn_mfma_f32_16x16x32_bf16(af[i], bfr[j], acc[i][j], 0, 0, 0);
        __syncthreads();
    }
#pragma unroll
    for (int i = 0; i < 4; ++i) {
#pragma unroll
        for (int r = 0; r < 4; ++r) {
            const int row = rowBase + wr + i * 16 + quad * 4 + r;
            if (row < M) {
#pragma unroll
                for (int j = 0; j < 4; ++j) {
                    const int col = colBase + wc + j * 16 + l15;
                    C[(size_t)row * HDIM + col] = f2bf(acc[i][j][r]);
                }
            }
        }
    }
}

// ---------- column stats: vectorized, ILP-unrolled, non-atomic partials ----------
__global__ __launch_bounds__(256) void k_colstats2(const u16* __restrict__ Cb,
                                                   float* __restrict__ statpart, int M) {
    const int t = threadIdx.x;
    const int roff = t >> 5;        // 0..7: row phase
    const int c0 = (t & 31) * 8;    // 8 columns per thread
    const int rpb = (M + 255) / 256;
    const int r0 = blockIdx.x * rpb;
    int r1 = r0 + rpb; if (r1 > M) r1 = M;
    float s[8], ss[8];
#pragma unroll
    for (int e = 0; e < 8; ++e) { s[e] = 0.f; ss[e] = 0.f; }
    int r = r0 + roff;
    for (; r + 8 < r1; r += 16) {
        uint4 a = *(const uint4*)(Cb + (size_t)r * HDIM + c0);
        uint4 b = *(const uint4*)(Cb + (size_t)(r + 8) * HDIM + c0);
        float fa[8], fb[8];
        up8(a, fa); up8(b, fb);
#pragma unroll
        for (int e = 0; e < 8; ++e) {
            s[e] += fa[e] + fb[e];
            ss[e] += fa[e] * fa[e] + fb[e] * fb[e];
        }
    }
    for (; r < r1; r += 8) {
        uint4 a = *(const uint4*)(Cb + (size_t)r * HDIM + c0);
        float fa[8];
        up8(a, fa);
#pragma unroll
        for (int e = 0; e < 8; ++e) { s[e] += fa[e]; ss[e] += fa[e] * fa[e]; }
    }
    __shared__ float Ls[8][256];
    __shared__ float Lq[8][256];
#pragma unroll
    for (int e = 0; e < 8; ++e) { Ls[roff][c0 + e] = s[e]; Lq[roff][c0 + e] = ss[e]; }
    __syncthreads();
    float a = 0.f, b = 0.f;
#pragma unroll
    for (int k = 0; k < 8; ++k) { a += Ls[k][t]; b += Lq[k][t]; }
    statpart[(size_t)blockIdx.x * 512 + t] = a;
    statpart[(size_t)blockIdx.x * 512 + 256 + t] = b;
}

// ---------- reduce per-block stat partials: stats[c] = sum_b statpart[b][c] ----------
__global__ void k_statred(const float* __restrict__ sp, float* __restrict__ stats) {
    const int c = blockIdx.x;  // 0..511
    float a = 0.f;
    for (int b = threadIdx.x; b < 256; b += 64) a += sp[(size_t)b * 512 + c];
#pragma unroll
    for (int off = 32; off > 0; off >>= 1) a += __shfl_down(a, off);
    if (threadIdx.x == 0) stats[c] = a;
}

__global__ void k_bnscale(const float* __restrict__ stats, const float* __restrict__ g,
                          const float* __restrict__ beta, float* __restrict__ sc,
                          float* __restrict__ sh, float invN) {
    int c = threadIdx.x;
    float mu = stats[c] * invN;
    float var = stats[HDIM + c] * invN - mu * mu;
    float s = g[c] * rsqrtf(var + 1e-5f);
    sc[c] = s;
    sh[c] = beta[c] - mu * s;
}

// ---------- h_next = relu(C*scale+shift) + identity (+res_b); optional fused dot ----------
// 32 elements (64 B) per thread; 8x16B loads issued up-front for Little's-law BW.
__global__ __launch_bounds__(256) void k_finalize2(
    const u16* __restrict__ Cb, const u16* __restrict__ iden,
    const float* __restrict__ sc, const float* __restrict__ sh,
    const float* __restrict__ resb, const float* __restrict__ w,
    u16* __restrict__ hout, float* __restrict__ nodedot) {
    const int i = blockIdx.x * 256 + threadIdx.x;   // tile id, 32 elems each; grid exact
    const size_t base = (size_t)i * 32;
    const int c0 = (i & 7) * 32;                    // column base within row
    const uint4* cp = (const uint4*)(Cb + base);
    const uint4* ip = (const uint4*)(iden + base);
    uint4 cv[4], iv[4];
#pragma unroll
    for (int q = 0; q < 4; ++q) cv[q] = cp[q];
#pragma unroll
    for (int q = 0; q < 4; ++q) iv[q] = ip[q];

    float dot = 0.f;
    uint4* op = (uint4*)(hout + base);
#pragma unroll
    for (int q = 0; q < 4; ++q) {
        float cf[8], df[8];
        up8(cv[q], cf); up8(iv[q], df);
        const float4 s0 = ((const float4*)(sc + c0 + q * 8))[0];
        const float4 s1 = ((const float4*)(sc + c0 + q * 8))[1];
        const float4 h0 = ((const float4*)(sh + c0 + q * 8))[0];
        const float4 h1 = ((const float4*)(sh + c0 + q * 8))[1];
        float scf[8] = {s0.x, s0.y, s0.z, s0.w, s1.x, s1.y, s1.z, s1.w};
        float shf[8] = {h0.x, h0.y, h0.z, h0.w, h1.x, h1.y, h1.z, h1.w};
        float rbf[8] = {0.f, 0.f, 0.f, 0.f, 0.f, 0.f, 0.f, 0.f};
        if (resb) {
            const float4 r0 = ((const float4*)(resb + c0 + q * 8))[0];
            const float4 r1 = ((const float4*)(resb + c0 + q * 8))[1];
            rbf[0] = r0.x; rbf[1] = r0.y; rbf[2] = r0.z; rbf[3] = r0.w;
            rbf[4] = r1.x; rbf[5] = r1.y; rbf[6] = r1.z; rbf[7] = r1.w;
        }
        float o[8];
#pragma unroll
        for (int e = 0; e < 8; ++e) {
            float v = cf[e] * scf[e] + shf[e];
            o[e] = fmaxf(v, 0.f) + df[e] + rbf[e];
        }
        if (nodedot) {
            const float4 w0 = ((const float4*)(w + c0 + q * 8))[0];
            const float4 w1 = ((const float4*)(w + c0 + q * 8))[1];
            dot += o[0] * w0.x + o[1] * w0.y + o[2] * w0.z + o[3] * w0.w
                 + o[4] * w1.x + o[5] * w1.y + o[6] * w1.z + o[7] * w1.w;
        }
        op[q] = make_uint4(pk2(o[0], o[1]), pk2(o[2], o[3]), pk2(o[4], o[5]), pk2(o[6], o[7]));
    }
    if (nodedot) {
        // 8 threads per row (consecutive lanes): segmented reduce
        dot += __shfl_down(dot, 4);
        dot += __shfl_down(dot, 2);
        dot += __shfl_down(dot, 1);
        if ((threadIdx.x & 7) == 0) nodedot[i >> 3] = dot;
    }
}

// ---------- readout stage 2: one block per graph, contiguous segment sum ----------
__global__ void k_pool(const float* __restrict__ nodedot, const int* __restrict__ gptr,
                       const float* __restrict__ lb, float* __restrict__ out) {
    const int g = blockIdx.x;
    const int r0 = gptr[g], r1 = gptr[g + 1];
    float s = 0.f;
    for (int i = r0 + threadIdx.x; i < r1; i += 256) s += nodedot[i];
#pragma unroll
    for (int off = 32; off > 0; off >>= 1) s += __shfl_down(s, off);
    __shared__ float red[4];
    const int wave = threadIdx.x >> 6;
    if ((threadIdx.x & 63) == 0) red[wave] = s;
    __syncthreads();
    if (threadIdx.x == 0) {
        float tot = red[0] + red[1] + red[2] + red[3];
        int c = r1 - r0; if (c < 1) c = 1;
        out[g] = tot / (float)c + lb[0];
    }
}

extern "C" void kernel_launch(void* const* d_in, const int* in_sizes, int n_in,
                              void* d_out, int out_size, void* d_ws, size_t ws_size,
                              hipStream_t stream) {
    const float* x     = (const float*)d_in[0];
    const int*   ei    = (const int*)d_in[1];
    const int*   batch = (const int*)d_in[2];
    const float* Wl1 = (const float*)d_in[3];
    const float* Wr1 = (const float*)d_in[5];
    const float* g1  = (const float*)d_in[6];
    const float* be1 = (const float*)d_in[7];
    const float* Wl2 = (const float*)d_in[8];
    const float* Wr2 = (const float*)d_in[10];
    const float* g2  = (const float*)d_in[11];
    const float* be2 = (const float*)d_in[12];
    const float* Wl3 = (const float*)d_in[13];
    const float* Wr3 = (const float*)d_in[15];
    const float* g3  = (const float*)d_in[16];
    const float* be3 = (const float*)d_in[17];
    const float* Wl4 = (const float*)d_in[18];
    const float* Wr4 = (const float*)d_in[20];
    const float* g4  = (const float*)d_in[21];
    const float* be4 = (const float*)d_in[22];
    const float* resW = (const float*)d_in[23];
    const float* resb = (const float*)d_in[24];
    const float* linW = (const float*)d_in[25];
    const float* linb = (const float*)d_in[26];
    float* out = (float*)d_out;

    char* p = (char*)d_ws;
    auto carve = [&](size_t bytes) -> char* {
        char* r = p;
        p += (bytes + 255) & ~(size_t)255;
        return r;
    };
    int*   cptr    = (int*)carve((size_t)(N_NODESC + 1) * 4);
    int*   counts  = (int*)carve((size_t)N_NODESC * 4);
    float* dinv    = (float*)carve((size_t)N_NODESC * 4);
    int*   gptr    = (int*)carve((N_GRAPHSC + 1) * 4);
    float* nodedot = (float*)carve((size_t)N_NODESC * 4);
    float* stats   = (float*)carve(512 * 4);
    float* statpart= (float*)carve((size_t)256 * 512 * 4);
    float* scale   = (float*)carve(256 * 4);
    float* shift   = (float*)carve(256 * 4);
    int*   bsum    = (int*)carve(SCAN_NB * 4);
    int*   boff    = (int*)carve(SCAN_NB * 4);
    int*   adj     = (int*)carve((size_t)N_EDGESC * 4);
    u16*   Wt1     = (u16*)carve(256 * 256 * 2);
    u16*   Wt2     = (u16*)carve(256 * 512 * 2);
    u16*   Wt3     = (u16*)carve(256 * 512 * 2);
    u16*   Wt4     = (u16*)carve(256 * 512 * 2);
    u16*   Rt      = (u16*)carve(256 * 128 * 2);
    u16*   xb      = (u16*)carve((size_t)N_NODESC * F_INC * 2);
    u16*   hA      = (u16*)carve((size_t)N_NODESC * HDIM * 2);
    u16*   hB      = (u16*)carve((size_t)N_NODESC * HDIM * 2);
    u16*   agg     = (u16*)carve((size_t)N_NODESC * HDIM * 2);  // aliased as res for layer 1
    u16*   Cb      = (u16*)carve((size_t)N_NODESC * HDIM * 2);

    // CSR-build temporaries alias big buffers that are dead during the build:
    unsigned int* P     = (unsigned int*)hA;  // 3.2 MB; dead before hA written (layer-1 finalize)
    unsigned int* epack = (unsigned int*)Cb;  // 6.4 MB; dead before Cb written (layer-1 gemm)
    u16*          Bp    = (u16*)hB;           // 1.6 MB; dead before hB written (layer-2 finalize)

    hipMemsetAsync(P, 0, (size_t)8 * N_NODESC * 4, stream);

    const int* srcp = ei;
    const int* dstp = ei + N_EDGESC;

    // weight prep + x conversion
    k_wcat<<<(256 * 256 + 255) / 256, 256, 0, stream>>>(Wl1, Wr1, 128, 128, Wt1);
    k_wcat<<<(256 * 512 + 255) / 256, 256, 0, stream>>>(Wl2, Wr2, 256, 256, Wt2);
    k_wcat<<<(256 * 512 + 255) / 256, 256, 0, stream>>>(Wl3, Wr3, 256, 256, Wt3);
    k_wcat<<<(256 * 512 + 255) / 256, 256, 0, stream>>>(Wl4, Wr4, 256, 256, Wt4);
    k_wcat<<<(256 * 128 + 255) / 256, 256, 0, stream>>>(resW, resW, 128, 0, Rt);
    k_f2bf4<<<(N_NODESC * F_INC / 4 + 255) / 256, 256, 0, stream>>>(x, xb, N_NODESC * F_INC / 4);

    // graph structure (no device-scope atomics anywhere)
    k_gfind<<<5, 64, 0, stream>>>(batch, gptr, N_NODESC);
    k_countP<<<(N_EDGESC + 1023) / 1024, 256, 0, stream>>>(dstp, P, epack, N_EDGESC);
    k_reduceP<<<(N_NODESC + 255) / 256, 256, 0, stream>>>(P, counts, dinv, Bp, N_NODESC);
    k_scan_bsum<<<SCAN_NB, 256, 0, stream>>>(counts, bsum, N_NODESC);
    k_scan_boff<<<1, 256, 0, stream>>>(bsum, boff, SCAN_NB);
    k_scan_write<<<SCAN_NB, 256, 0, stream>>>(counts, boff, cptr, N_NODESC);
    k_fill2<<<(N_EDGESC + 1023) / 1024, 256, 0, stream>>>(srcp, dstp, epack, cptr, Bp, adj, N_EDGESC);

    dim3 gGemm(782, 2);
    const float invN = 1.0f / (float)N_NODESC;
    const int finBlocks = N_NODESC * HDIM / 32 / 256;  // 3125, exact

    // ---- layer 1 ----
    k_aggregate<128><<<25000, 256, 0, stream>>>(xb, cptr, adj, dinv, agg, N_NODESC);
    k_gemm<<<gGemm, 256, 0, stream>>>(agg, 128, xb, 128, Wt1, Cb, N_NODESC);
    k_gemm<<<gGemm, 256, 0, stream>>>(xb, 128, xb, 0, Rt, agg, N_NODESC);  // res reuses agg
    k_colstats2<<<256, 256, 0, stream>>>(Cb, statpart, N_NODESC);
    k_statred<<<512, 64, 0, stream>>>(statpart, stats);
    k_bnscale<<<1, 256, 0, stream>>>(stats, g1, be1, scale, shift, invN);
    k_finalize2<<<finBlocks, 256, 0, stream>>>(Cb, agg, scale, shift, resb, nullptr, hA, nullptr);

    // ---- layer 2 ----
    k_aggregate<256><<<25000, 256, 0, stream>>>(hA, cptr, adj, dinv, agg, N_NODESC);
    k_gemm<<<gGemm, 256, 0, stream>>>(agg, 256, hA, 256, Wt2, Cb, N_NODESC);
    k_colstats2<<<256, 256, 0, stream>>>(Cb, statpart, N_NODESC);
    k_statred<<<512, 64, 0, stream>>>(statpart, stats);
    k_bnscale<<<1, 256, 0, stream>>>(stats, g2, be2, scale, shift, invN);
    k_finalize2<<<finBlocks, 256, 0, stream>>>(Cb, hA, scale, shift, nullptr, nullptr, hB, nullptr);

    // ---- layer 3 ----
    k_aggregate<256><<<25000, 256, 0, stream>>>(hB, cptr, adj, dinv, agg, N_NODESC);
    k_gemm<<<gGemm, 256, 0, stream>>>(agg, 256, hB, 256, Wt3, Cb, N_NODESC);
    k_colstats2<<<256, 256, 0, stream>>>(Cb, statpart, N_NODESC);
    k_statred<<<512, 64, 0, stream>>>(statpart, stats);
    k_bnscale<<<1, 256, 0, stream>>>(stats, g3, be3, scale, shift, invN);
    k_finalize2<<<finBlocks, 256, 0, stream>>>(Cb, hB, scale, shift, nullptr, nullptr, hA, nullptr);

    // ---- layer 4 (fused per-node dot with lin_W) ----
    k_aggregate<256><<<25000, 256, 0, stream>>>(hA, cptr, adj, dinv, agg, N_NODESC);
    k_gemm<<<gGemm, 256, 0, stream>>>(agg, 256, hA, 256, Wt4, Cb, N_NODESC);
    k_colstats2<<<256, 256, 0, stream>>>(Cb, statpart, N_NODESC);
    k_statred<<<512, 64, 0, stream>>>(statpart, stats);
    k_bnscale<<<1, 256, 0, stream>>>(stats, g4, be4, scale, shift, invN);
    k_finalize2<<<finBlocks, 256, 0, stream>>>(Cb, hA, scale, shift, nullptr, linW, hB, nodedot);

    // ---- pooled mean + lin_b ----
    k_pool<<<N_GRAPHSC, 256, 0, stream>>>(nodedot, gptr, linb, out);
}

// Round 5
// 1152.859 us; speedup vs baseline: 1.9851x; 1.0420x over previous
//
#include <hip/hip_runtime.h>

typedef unsigned short u16;
typedef __attribute__((ext_vector_type(8))) short short8;
typedef __attribute__((ext_vector_type(4))) float floatx4;

#define N_NODESC 100000
#define N_EDGESC 1600000
#define N_GRAPHSC 256
#define F_INC 128
#define HDIM 256
#define SCAN_CHUNK 512
#define SCAN_NB ((N_NODESC + SCAN_CHUNK - 1) / SCAN_CHUNK)  // 196
#define GEMM_BX 782
#define GEMM_NBLK (GEMM_BX * 2)

__device__ __forceinline__ float bf2f(u16 u) {
    union { unsigned int i; float f; } v; v.i = ((unsigned int)u) << 16; return v.f;
}
__device__ __forceinline__ u16 f2bf(float f) {
    union { float f; unsigned int i; } v; v.f = f;
    unsigned int b = v.i;
    b += 0x7fffu + ((b >> 16) & 1u);
    return (u16)(b >> 16);
}
__device__ __forceinline__ void up8(uint4 v, float* f) {
    f[0] = bf2f((u16)(v.x & 0xffff)); f[1] = bf2f((u16)(v.x >> 16));
    f[2] = bf2f((u16)(v.y & 0xffff)); f[3] = bf2f((u16)(v.y >> 16));
    f[4] = bf2f((u16)(v.z & 0xffff)); f[5] = bf2f((u16)(v.z >> 16));
    f[6] = bf2f((u16)(v.w & 0xffff)); f[7] = bf2f((u16)(v.w >> 16));
}
__device__ __forceinline__ unsigned int pk2(float a, float b) {
    return (unsigned int)f2bf(a) | ((unsigned int)f2bf(b) << 16);
}
// XCC_ID hwreg (id=20) — measured working on gfx950 (learn_hip m09)
__device__ __forceinline__ int get_xcd() {
    int x;
    asm volatile("s_getreg_b32 %0, hwreg(20, 0, 4)" : "=s"(x));
    return x & 7;
}

// ---------- weight prep: out[c*K + k] = (k<K1 ? Wl[k][c] : Wr[k-K1][c]) as bf16 ----------
__global__ void k_wcat(const float* __restrict__ Wl, const float* __restrict__ Wr,
                       int K1, int K2, u16* __restrict__ out) {
    int K = K1 + K2;
    int idx = blockIdx.x * 256 + threadIdx.x;
    if (idx >= 256 * K) return;
    int c = idx / K, k = idx - c * K;
    float v = (k < K1) ? Wl[k * 256 + c] : Wr[(k - K1) * 256 + c];
    out[idx] = f2bf(v);
}

// ---------- fp32 -> bf16 vectorized convert ----------
__global__ void k_f2bf4(const float* __restrict__ in, u16* __restrict__ out, int n4) {
    int i = blockIdx.x * 256 + threadIdx.x;
    if (i >= n4) return;
    float4 v = ((const float4*)in)[i];
    ushort4 o = make_ushort4(f2bf(v.x), f2bf(v.y), f2bf(v.z), f2bf(v.w));
    ((ushort4*)out)[i] = o;
}

// ---------- edge count: per-XCD partial histograms, XCD-local (workgroup-scope) atomics ----------
__global__ void k_countP(const int* __restrict__ dst, unsigned int* __restrict__ P,
                         unsigned int* __restrict__ epack, int E) {
    const int xcd = get_xcd();
    unsigned int* Px = P + (size_t)xcd * N_NODESC;
    const int e0 = blockIdx.x * 1024 + threadIdx.x;
#pragma unroll
    for (int l = 0; l < 4; ++l) {
        int e = e0 + l * 256;
        if (e < E) {
            int d = dst[e];
            unsigned int pos = __hip_atomic_fetch_add(&Px[d], 1u, __ATOMIC_RELAXED,
                                                      __HIP_MEMORY_SCOPE_WORKGROUP);
            epack[e] = ((unsigned int)xcd << 16) | pos;
        }
    }
}

// ---------- reduce partials: counts, 1/deg, per-(node,xcd) base offsets ----------
__global__ void k_reduceP(const unsigned int* __restrict__ P, int* __restrict__ counts,
                          float* __restrict__ dinv, u16* __restrict__ Bp, int n) {
    int d = blockIdx.x * 256 + threadIdx.x;
    if (d >= n) return;
    unsigned int s = 0;
    u16 b[8];
#pragma unroll
    for (int x = 0; x < 8; ++x) {
        b[x] = (u16)s;
        s += P[(size_t)x * n + d];
    }
    counts[d] = (int)s;
    dinv[d] = 1.0f / (float)(s > 1u ? s : 1u);
    ushort4* bp = (ushort4*)(Bp + (size_t)d * 8);
    bp[0] = make_ushort4(b[0], b[1], b[2], b[3]);
    bp[1] = make_ushort4(b[4], b[5], b[6], b[7]);
}

// ---------- 3-phase scan over counts -> csr_ptr ----------
__global__ void k_scan_bsum(const int* __restrict__ cnt, int* __restrict__ bsum, int n) {
    __shared__ int ts[256];
    int t = threadIdx.x;
    int i0 = blockIdx.x * SCAN_CHUNK + t * 2;
    int c0 = (i0 < n) ? cnt[i0] : 0;
    int c1 = (i0 + 1 < n) ? cnt[i0 + 1] : 0;
    ts[t] = c0 + c1;
    __syncthreads();
    for (int off = 128; off > 0; off >>= 1) {
        if (t < off) ts[t] += ts[t + off];
        __syncthreads();
    }
    if (t == 0) bsum[blockIdx.x] = ts[0];
}

__global__ void k_scan_boff(const int* __restrict__ bsum, int* __restrict__ boff, int nb) {
    __shared__ int ts[256];
    int t = threadIdx.x;
    int v = (t < nb) ? bsum[t] : 0;
    ts[t] = v;
    __syncthreads();
    for (int off = 1; off < 256; off <<= 1) {
        int u = (t >= off) ? ts[t - off] : 0;
        __syncthreads();
        ts[t] += u;
        __syncthreads();
    }
    if (t < nb) boff[t] = ts[t] - v;  // exclusive
}

__global__ void k_scan_write(const int* __restrict__ cnt, const int* __restrict__ boff,
                             int* __restrict__ cptr, int n) {
    __shared__ int ts[256];
    int t = threadIdx.x;
    int i0 = blockIdx.x * SCAN_CHUNK + t * 2;
    int c0 = (i0 < n) ? cnt[i0] : 0;
    int c1 = (i0 + 1 < n) ? cnt[i0 + 1] : 0;
    int ms = c0 + c1;
    ts[t] = ms;
    __syncthreads();
    for (int off = 1; off < 256; off <<= 1) {
        int u = (t >= off) ? ts[t - off] : 0;
        __syncthreads();
        ts[t] += u;
        __syncthreads();
    }
    int excl = ts[t] - ms + boff[blockIdx.x];
    if (i0 < n) cptr[i0] = excl;
    if (i0 + 1 < n) cptr[i0 + 1] = excl + c0;
    if (i0 == n - 1) cptr[n] = excl + c0;
    else if (i0 + 1 == n - 1) cptr[n] = excl + c0 + c1;
}

// ---------- CSR fill: slot fully determined, zero atomics ----------
__global__ void k_fill2(const int* __restrict__ src, const int* __restrict__ dst,
                        const unsigned int* __restrict__ epack,
                        const int* __restrict__ cptr, const u16* __restrict__ Bp,
                        int* __restrict__ adj, int E) {
    const int e0 = blockIdx.x * 1024 + threadIdx.x;
#pragma unroll
    for (int l = 0; l < 4; ++l) {
        int e = e0 + l * 256;
        if (e < E) {
            int d = dst[e];
            unsigned int pk = epack[e];
            int x = (int)(pk >> 16);
            int pos = (int)(pk & 0xFFFFu);
            adj[cptr[d] + (int)Bp[(size_t)d * 8 + x] + pos] = src[e];
        }
    }
}

// ---------- graph ranges: batch is sorted -> binary search lower bounds ----------
__global__ void k_gfind(const int* __restrict__ batch, int* __restrict__ gptr, int n) {
    int g = blockIdx.x * 64 + threadIdx.x;
    if (g > N_GRAPHSC) return;
    int lo = 0, hi = n;
    while (lo < hi) {
        int mid = (lo + hi) >> 1;
        if (batch[mid] < g) lo = mid + 1; else hi = mid;
    }
    gptr[g] = lo;
}

// ---------- aggregation v2: lane-parallel adj fetch + shfl broadcast, 8-deep gather ----------
template <int F>
__global__ void k_aggregate2(const u16* __restrict__ hin, const int* __restrict__ cptr,
                             const int* __restrict__ adj, const float* __restrict__ di,
                             u16* __restrict__ out, int n) {
    constexpr int V = F / 64;  // u16 elems per lane
    const int lane = threadIdx.x & 63;
    const int node = blockIdx.x * 4 + (threadIdx.x >> 6);
    if (node >= n) return;
    const int p0 = cptr[node], p1 = cptr[node + 1];
    const u16* base = hin + (size_t)lane * V;
    const float d = di[node];
    float a[V];
#pragma unroll
    for (int e = 0; e < V; ++e) a[e] = 0.f;

    int j = p0;
    while (j < p1) {
        int take = p1 - j; if (take > 64) take = 64;
        int myidx = (lane < take) ? adj[j + lane] : 0;
        int k = 0;
        for (; k + 8 <= take; k += 8) {
            int s[8];
#pragma unroll
            for (int u = 0; u < 8; ++u) s[u] = __shfl(myidx, k + u);
            if constexpr (V == 4) {
                ushort4 hv[8];
#pragma unroll
                for (int u = 0; u < 8; ++u) hv[u] = *(const ushort4*)(base + (size_t)s[u] * F);
#pragma unroll
                for (int u = 0; u < 8; ++u) {
                    a[0] += bf2f(hv[u].x); a[1] += bf2f(hv[u].y);
                    a[2] += bf2f(hv[u].z); a[3] += bf2f(hv[u].w);
                }
            } else {
                ushort2 hv[8];
#pragma unroll
                for (int u = 0; u < 8; ++u) hv[u] = *(const ushort2*)(base + (size_t)s[u] * F);
#pragma unroll
                for (int u = 0; u < 8; ++u) { a[0] += bf2f(hv[u].x); a[1] += bf2f(hv[u].y); }
            }
        }
        for (; k < take; ++k) {
            int s0 = __shfl(myidx, k);
            if constexpr (V == 4) {
                ushort4 hv = *(const ushort4*)(base + (size_t)s0 * F);
                a[0] += bf2f(hv.x); a[1] += bf2f(hv.y); a[2] += bf2f(hv.z); a[3] += bf2f(hv.w);
            } else {
                ushort2 hv = *(const ushort2*)(base + (size_t)s0 * F);
                a[0] += bf2f(hv.x); a[1] += bf2f(hv.y);
            }
        }
        j += take;
    }
    if constexpr (V == 4) {
        ushort4 o = make_ushort4(f2bf(a[0] * d), f2bf(a[1] * d), f2bf(a[2] * d), f2bf(a[3] * d));
        *(ushort4*)(out + (size_t)node * F + lane * 4) = o;
    } else {
        ushort2 o; o.x = f2bf(a[0] * d); o.y = f2bf(a[1] * d);
        *(ushort2*)(out + (size_t)node * F + lane * 2) = o;
    }
}

// ---------- GEMM + fused column-stat partials ----------
__global__ __launch_bounds__(256) void k_gemm(
    const u16* __restrict__ A1, int K1,
    const u16* __restrict__ A2, int K2,
    const u16* __restrict__ Wt,
    u16* __restrict__ C, int M, float* __restrict__ statpart) {
    const int K = K1 + K2;
    __shared__ __align__(16) u16 Al[128 * 40];
    __shared__ __align__(16) u16 Bl[128 * 40];
    __shared__ float Ssum[2][128];
    __shared__ float Ssq[2][128];
    const int t = threadIdx.x;
    const int lane = t & 63;
    const int wave = t >> 6;
    const int wr = (wave >> 1) * 64, wc = (wave & 1) * 64;
    const int quad = lane >> 4, l15 = lane & 15;
    const int rowBase = blockIdx.x * 128;
    const int colBase = blockIdx.y * 128;

    floatx4 acc[4][4];
#pragma unroll
    for (int i = 0; i < 4; ++i)
#pragma unroll
        for (int j = 0; j < 4; ++j)
            acc[i][j] = (floatx4){0.f, 0.f, 0.f, 0.f};

    const int r0 = t >> 2;             // 0..63
    const int ch0 = (t & 3) * 8;       // 0,8,16,24 (elements)

    for (int kt = 0; kt < K; kt += 32) {
        const u16* As; int lda, kloc;
        if (kt < K1) { As = A1; lda = K1; kloc = kt; }
        else         { As = A2; lda = K2; kloc = kt - K1; }
#pragma unroll
        for (int l = 0; l < 2; ++l) {
            const int r = r0 + l * 64;
            const int grow = rowBase + r;
            uint4 va = make_uint4(0u, 0u, 0u, 0u);
            if (grow < M) va = *(const uint4*)(As + (size_t)grow * lda + (kloc + ch0));
            *(uint4*)(Al + r * 40 + ch0) = va;
            uint4 vb = *(const uint4*)(Wt + (size_t)(colBase + r) * K + (kt + ch0));
            *(uint4*)(Bl + r * 40 + ch0) = vb;
        }
        __syncthreads();
        short8 af[4], bfr[4];
#pragma unroll
        for (int i = 0; i < 4; ++i) af[i] = *(const short8*)(Al + (wr + i * 16 + l15) * 40 + quad * 8);
#pragma unroll
        for (int j = 0; j < 4; ++j) bfr[j] = *(const short8*)(Bl + (wc + j * 16 + l15) * 40 + quad * 8);
#pragma unroll
        for (int i = 0; i < 4; ++i)
#pragma unroll
            for (int j = 0; j < 4; ++j)
                acc[i][j] = __builtin_amdgcn_mfma_f32_16x16x32_bf16(af[i], bfr[j], acc[i][j], 0, 0, 0);
        __syncthreads();
    }
    // fused column stats (pad rows have zero A -> zero acc, contribute nothing)
    if (statpart) {
#pragma unroll
        for (int j = 0; j < 4; ++j) {
            float s = 0.f, q = 0.f;
#pragma unroll
            for (int i = 0; i < 4; ++i)
#pragma unroll
                for (int r = 0; r < 4; ++r) {
                    float v = acc[i][j][r];
                    s += v; q += v * v;
                }
            s += __shfl_down(s, 32); s += __shfl_down(s, 16);
            q += __shfl_down(q, 32); q += __shfl_down(q, 16);
            if (lane < 16) {
                Ssum[wr >> 6][wc + j * 16 + l15] = s;
                Ssq[wr >> 6][wc + j * 16 + l15] = q;
            }
        }
        __syncthreads();
        if (t < 128) {
            const size_t bid = (size_t)blockIdx.y * GEMM_BX + blockIdx.x;
            statpart[bid * 256 + t] = Ssum[0][t] + Ssum[1][t];
            statpart[bid * 256 + 128 + t] = Ssq[0][t] + Ssq[1][t];
        }
    }
#pragma unroll
    for (int i = 0; i < 4; ++i) {
#pragma unroll
        for (int r = 0; r < 4; ++r) {
            const int row = rowBase + wr + i * 16 + quad * 4 + r;
            if (row < M) {
#pragma unroll
                for (int j = 0; j < 4; ++j) {
                    const int col = colBase + wc + j * 16 + l15;
                    C[(size_t)row * HDIM + col] = f2bf(acc[i][j][r]);
                }
            }
        }
    }
}

// ---------- reduce per-block stat partials ----------
__global__ void k_statred2(const float* __restrict__ sp, float* __restrict__ stats) {
    const int cc = blockIdx.x;                 // 0..511
    const int col = cc & 255;
    const int kind = (cc >> 8) * 128;          // 0 for sum, 128 for sumsq
    const size_t base = (size_t)(col >> 7) * GEMM_BX;
    const int off = kind + (col & 127);
    float a = 0.f;
    for (int bx = threadIdx.x; bx < GEMM_BX; bx += 64)
        a += sp[(base + bx) * 256 + off];
#pragma unroll
    for (int o = 32; o > 0; o >>= 1) a += __shfl_down(a, o);
    if (threadIdx.x == 0) stats[cc] = a;
}

__global__ void k_bnscale(const float* __restrict__ stats, const float* __restrict__ g,
                          const float* __restrict__ beta, float* __restrict__ sc,
                          float* __restrict__ sh, float invN) {
    int c = threadIdx.x;
    float mu = stats[c] * invN;
    float var = stats[HDIM + c] * invN - mu * mu;
    float s = g[c] * rsqrtf(var + 1e-5f);
    sc[c] = s;
    sh[c] = beta[c] - mu * s;
}

// ---------- h_next = relu(C*scale+shift) + identity (+res_b); optional fused dot ----------
__global__ __launch_bounds__(256) void k_finalize2(
    const u16* __restrict__ Cb, const u16* __restrict__ iden,
    const float* __restrict__ sc, const float* __restrict__ sh,
    const float* __restrict__ resb, const float* __restrict__ w,
    u16* __restrict__ hout, float* __restrict__ nodedot) {
    const int i = blockIdx.x * 256 + threadIdx.x;   // tile id, 32 elems each; grid exact
    const size_t base = (size_t)i * 32;
    const int c0 = (i & 7) * 32;                    // column base within row
    const uint4* cp = (const uint4*)(Cb + base);
    const uint4* ip = (const uint4*)(iden + base);
    uint4 cv[4], iv[4];
#pragma unroll
    for (int q = 0; q < 4; ++q) cv[q] = cp[q];
#pragma unroll
    for (int q = 0; q < 4; ++q) iv[q] = ip[q];

    float dot = 0.f;
    uint4* op = (uint4*)(hout + base);
#pragma unroll
    for (int q = 0; q < 4; ++q) {
        float cf[8], df[8];
        up8(cv[q], cf); up8(iv[q], df);
        const float4 s0 = ((const float4*)(sc + c0 + q * 8))[0];
        const float4 s1 = ((const float4*)(sc + c0 + q * 8))[1];
        const float4 h0 = ((const float4*)(sh + c0 + q * 8))[0];
        const float4 h1 = ((const float4*)(sh + c0 + q * 8))[1];
        float scf[8] = {s0.x, s0.y, s0.z, s0.w, s1.x, s1.y, s1.z, s1.w};
        float shf[8] = {h0.x, h0.y, h0.z, h0.w, h1.x, h1.y, h1.z, h1.w};
        float rbf[8] = {0.f, 0.f, 0.f, 0.f, 0.f, 0.f, 0.f, 0.f};
        if (resb) {
            const float4 r0 = ((const float4*)(resb + c0 + q * 8))[0];
            const float4 r1 = ((const float4*)(resb + c0 + q * 8))[1];
            rbf[0] = r0.x; rbf[1] = r0.y; rbf[2] = r0.z; rbf[3] = r0.w;
            rbf[4] = r1.x; rbf[5] = r1.y; rbf[6] = r1.z; rbf[7] = r1.w;
        }
        float o[8];
#pragma unroll
        for (int e = 0; e < 8; ++e) {
            float v = cf[e] * scf[e] + shf[e];
            o[e] = fmaxf(v, 0.f) + df[e] + rbf[e];
        }
        if (nodedot) {
            const float4 w0 = ((const float4*)(w + c0 + q * 8))[0];
            const float4 w1 = ((const float4*)(w + c0 + q * 8))[1];
            dot += o[0] * w0.x + o[1] * w0.y + o[2] * w0.z + o[3] * w0.w
                 + o[4] * w1.x + o[5] * w1.y + o[6] * w1.z + o[7] * w1.w;
        }
        op[q] = make_uint4(pk2(o[0], o[1]), pk2(o[2], o[3]), pk2(o[4], o[5]), pk2(o[6], o[7]));
    }
    if (nodedot) {
        dot += __shfl_down(dot, 4);
        dot += __shfl_down(dot, 2);
        dot += __shfl_down(dot, 1);
        if ((threadIdx.x & 7) == 0) nodedot[i >> 3] = dot;
    }
}

// ---------- readout stage 2: one block per graph, contiguous segment sum ----------
__global__ void k_pool(const float* __restrict__ nodedot, const int* __restrict__ gptr,
                       const float* __restrict__ lb, float* __restrict__ out) {
    const int g = blockIdx.x;
    const int r0 = gptr[g], r1 = gptr[g + 1];
    float s = 0.f;
    for (int i = r0 + threadIdx.x; i < r1; i += 256) s += nodedot[i];
#pragma unroll
    for (int off = 32; off > 0; off >>= 1) s += __shfl_down(s, off);
    __shared__ float red[4];
    const int wave = threadIdx.x >> 6;
    if ((threadIdx.x & 63) == 0) red[wave] = s;
    __syncthreads();
    if (threadIdx.x == 0) {
        float tot = red[0] + red[1] + red[2] + red[3];
        int c = r1 - r0; if (c < 1) c = 1;
        out[g] = tot / (float)c + lb[0];
    }
}

extern "C" void kernel_launch(void* const* d_in, const int* in_sizes, int n_in,
                              void* d_out, int out_size, void* d_ws, size_t ws_size,
                              hipStream_t stream) {
    const float* x     = (const float*)d_in[0];
    const int*   ei    = (const int*)d_in[1];
    const int*   batch = (const int*)d_in[2];
    const float* Wl1 = (const float*)d_in[3];
    const float* Wr1 = (const float*)d_in[5];
    const float* g1  = (const float*)d_in[6];
    const float* be1 = (const float*)d_in[7];
    const float* Wl2 = (const float*)d_in[8];
    const float* Wr2 = (const float*)d_in[10];
    const float* g2  = (const float*)d_in[11];
    const float* be2 = (const float*)d_in[12];
    const float* Wl3 = (const float*)d_in[13];
    const float* Wr3 = (const float*)d_in[15];
    const float* g3  = (const float*)d_in[16];
    const float* be3 = (const float*)d_in[17];
    const float* Wl4 = (const float*)d_in[18];
    const float* Wr4 = (const float*)d_in[20];
    const float* g4  = (const float*)d_in[21];
    const float* be4 = (const float*)d_in[22];
    const float* resW = (const float*)d_in[23];
    const float* resb = (const float*)d_in[24];
    const float* linW = (const float*)d_in[25];
    const float* linb = (const float*)d_in[26];
    float* out = (float*)d_out;

    char* p = (char*)d_ws;
    auto carve = [&](size_t bytes) -> char* {
        char* r = p;
        p += (bytes + 255) & ~(size_t)255;
        return r;
    };
    int*   cptr    = (int*)carve((size_t)(N_NODESC + 1) * 4);
    int*   counts  = (int*)carve((size_t)N_NODESC * 4);
    float* dinv    = (float*)carve((size_t)N_NODESC * 4);
    int*   gptr    = (int*)carve((N_GRAPHSC + 1) * 4);
    float* nodedot = (float*)carve((size_t)N_NODESC * 4);
    float* stats   = (float*)carve(512 * 4);
    float* statpart= (float*)carve((size_t)GEMM_NBLK * 256 * 4);
    float* scale   = (float*)carve(256 * 4);
    float* shift   = (float*)carve(256 * 4);
    int*   bsum    = (int*)carve(SCAN_NB * 4);
    int*   boff    = (int*)carve(SCAN_NB * 4);
    int*   adj     = (int*)carve((size_t)N_EDGESC * 4);
    u16*   Wt1     = (u16*)carve(256 * 256 * 2);
    u16*   Wt2     = (u16*)carve(256 * 512 * 2);
    u16*   Wt3     = (u16*)carve(256 * 512 * 2);
    u16*   Wt4     = (u16*)carve(256 * 512 * 2);
    u16*   Rt      = (u16*)carve(256 * 128 * 2);
    u16*   xb      = (u16*)carve((size_t)N_NODESC * F_INC * 2);
    u16*   hA      = (u16*)carve((size_t)N_NODESC * HDIM * 2);
    u16*   hB      = (u16*)carve((size_t)N_NODESC * HDIM * 2);
    u16*   agg     = (u16*)carve((size_t)N_NODESC * HDIM * 2);  // aliased as res for layer 1
    u16*   Cb      = (u16*)carve((size_t)N_NODESC * HDIM * 2);

    // CSR-build temporaries alias big buffers that are dead during the build:
    unsigned int* P     = (unsigned int*)hA;  // 3.2 MB; dead before hA written (layer-1 finalize)
    unsigned int* epack = (unsigned int*)Cb;  // 6.4 MB; dead before Cb written (layer-1 gemm)
    u16*          Bp    = (u16*)hB;           // 1.6 MB; dead before hB written (layer-2 finalize)

    hipMemsetAsync(P, 0, (size_t)8 * N_NODESC * 4, stream);

    const int* srcp = ei;
    const int* dstp = ei + N_EDGESC;

    // weight prep + x conversion
    k_wcat<<<(256 * 256 + 255) / 256, 256, 0, stream>>>(Wl1, Wr1, 128, 128, Wt1);
    k_wcat<<<(256 * 512 + 255) / 256, 256, 0, stream>>>(Wl2, Wr2, 256, 256, Wt2);
    k_wcat<<<(256 * 512 + 255) / 256, 256, 0, stream>>>(Wl3, Wr3, 256, 256, Wt3);
    k_wcat<<<(256 * 512 + 255) / 256, 256, 0, stream>>>(Wl4, Wr4, 256, 256, Wt4);
    k_wcat<<<(256 * 128 + 255) / 256, 256, 0, stream>>>(resW, resW, 128, 0, Rt);
    k_f2bf4<<<(N_NODESC * F_INC / 4 + 255) / 256, 256, 0, stream>>>(x, xb, N_NODESC * F_INC / 4);

    // graph structure (no device-scope atomics anywhere)
    k_gfind<<<5, 64, 0, stream>>>(batch, gptr, N_NODESC);
    k_countP<<<(N_EDGESC + 1023) / 1024, 256, 0, stream>>>(dstp, P, epack, N_EDGESC);
    k_reduceP<<<(N_NODESC + 255) / 256, 256, 0, stream>>>(P, counts, dinv, Bp, N_NODESC);
    k_scan_bsum<<<SCAN_NB, 256, 0, stream>>>(counts, bsum, N_NODESC);
    k_scan_boff<<<1, 256, 0, stream>>>(bsum, boff, SCAN_NB);
    k_scan_write<<<SCAN_NB, 256, 0, stream>>>(counts, boff, cptr, N_NODESC);
    k_fill2<<<(N_EDGESC + 1023) / 1024, 256, 0, stream>>>(srcp, dstp, epack, cptr, Bp, adj, N_EDGESC);

    dim3 gGemm(GEMM_BX, 2);
    const float invN = 1.0f / (float)N_NODESC;
    const int finBlocks = N_NODESC * HDIM / 32 / 256;  // 3125, exact

    // ---- layer 1 ----
    k_aggregate2<128><<<25000, 256, 0, stream>>>(xb, cptr, adj, dinv, agg, N_NODESC);
    k_gemm<<<gGemm, 256, 0, stream>>>(agg, 128, xb, 128, Wt1, Cb, N_NODESC, statpart);
    k_gemm<<<gGemm, 256, 0, stream>>>(xb, 128, xb, 0, Rt, agg, N_NODESC, nullptr);  // res reuses agg
    k_statred2<<<512, 64, 0, stream>>>(statpart, stats);
    k_bnscale<<<1, 256, 0, stream>>>(stats, g1, be1, scale, shift, invN);
    k_finalize2<<<finBlocks, 256, 0, stream>>>(Cb, agg, scale, shift, resb, nullptr, hA, nullptr);

    // ---- layer 2 ----
    k_aggregate2<256><<<25000, 256, 0, stream>>>(hA, cptr, adj, dinv, agg, N_NODESC);
    k_gemm<<<gGemm, 256, 0, stream>>>(agg, 256, hA, 256, Wt2, Cb, N_NODESC, statpart);
    k_statred2<<<512, 64, 0, stream>>>(statpart, stats);
    k_bnscale<<<1, 256, 0, stream>>>(stats, g2, be2, scale, shift, invN);
    k_finalize2<<<finBlocks, 256, 0, stream>>>(Cb, hA, scale, shift, nullptr, nullptr, hB, nullptr);

    // ---- layer 3 ----
    k_aggregate2<256><<<25000, 256, 0, stream>>>(hB, cptr, adj, dinv, agg, N_NODESC);
    k_gemm<<<gGemm, 256, 0, stream>>>(agg, 256, hB, 256, Wt3, Cb, N_NODESC, statpart);
    k_statred2<<<512, 64, 0, stream>>>(statpart, stats);
    k_bnscale<<<1, 256, 0, stream>>>(stats, g3, be3, scale, shift, invN);
    k_finalize2<<<finBlocks, 256, 0, stream>>>(Cb, hB, scale, shift, nullptr, nullptr, hA, nullptr);

    // ---- layer 4 (fused per-node dot with lin_W) ----
    k_aggregate2<256><<<25000, 256, 0, stream>>>(hA, cptr, adj, dinv, agg, N_NODESC);
    k_gemm<<<gGemm, 256, 0, stream>>>(agg, 256, hA, 256, Wt4, Cb, N_NODESC, statpart);
    k_statred2<<<512, 64, 0, stream>>>(statpart, stats);
    k_bnscale<<<1, 256, 0, stream>>>(stats, g4, be4, scale, shift, invN);
    k_finalize2<<<finBlocks, 256, 0, stream>>>(Cb, hA, scale, shift, nullptr, linW, hB, nodedot);

    // ---- pooled mean + lin_b ----
    k_pool<<<N_GRAPHSC, 256, 0, stream>>>(nodedot, gptr, linb, out);
}